// Round 9
// baseline (782.596 us; speedup 1.0000x reference)
//
#include <hip/hip_runtime.h>
#include <hip/hip_bf16.h>

#define BB 8
#define TT 168
#define NN 425
#define EE 2048
#define II 128
#define HH 256
#define F1 10
#define F2 32
#define BT (BB*TT)       // 1344
#define K2 (NN*F2)       // 13600
#define N2 (2*NN)        // 850

// MFMA LSTM: wave w owns units [32w,32w+32) x all 4 gates = 128 rows of Whh,
// as 8 j-tiles (j>>1 = gate i,f,g,o; j&1 = unit half) x 8 kc (K=256/32).
// B-frag(j,kc) lane l: row=(j>>1)*256+32w+(j&1)*16+(l&15), k=32kc+8(l>>4)..+8.
// Residency: j<5 all kc in AGPR (40) + j==7,kc<6 (6) = 46 AGPR frags;
// LDS: j==5 (8) + j==6 (8) + j==7,kc>=6 (2) = 18 frags -> 144 KB.
#define BREG_PW 46
#define BLDS_PW 18
#define BREG_N (8*BREG_PW*64)   // 23552 h8
#define BLDS_N (8*BLDS_PW*64)   // 9216 h8 = 144 KB

typedef _Float16 h2 __attribute__((ext_vector_type(2)));
typedef _Float16 h8 __attribute__((ext_vector_type(8)));
typedef short bf16x8 __attribute__((ext_vector_type(8)));
typedef float f32x4 __attribute__((ext_vector_type(4)));

__device__ __forceinline__ float relu_(float x){ return fmaxf(x, 0.f); }
__device__ __forceinline__ float sigmoid_(float x){ return 1.f/(1.f + expf(-x)); }

// MFMA with B from AGPR (allocator-managed) / from VGPR (LDS-loaded)
#define MFMA_AG(ACC, AV, BV) \
    asm volatile("v_mfma_f32_16x16x32_f16 %0, %1, %2, %0" \
                 : "+v"(ACC) : "v"(AV), "a"(BV))
#define MFMA_VG(ACC, AV, BV) \
    asm volatile("v_mfma_f32_16x16x32_f16 %0, %1, %2, %0" \
                 : "+v"(ACC) : "v"(AV), "v"(BV))

// ---------------- GCN: two layers fused, one block per (b,t) graph ----------
__global__ __launch_bounds__(256) void gcn_kernel(
    const float* __restrict__ nf, const int* __restrict__ esrc,
    const int* __restrict__ edst, const float* __restrict__ ew,
    const float* __restrict__ Wg1, const float* __restrict__ bg1,
    const float* __restrict__ Wg2, const float* __restrict__ bg2,
    __hip_bfloat16* __restrict__ x2g)
{
    __shared__ float xs[NN];
    __shared__ float dinv[NN];
    __shared__ float agg1[NN];
    __shared__ float nrm[EE];
    __shared__ float x1[NN*F1];
    __shared__ float agg2[NN*F1];
    __shared__ float wg1s[F1], bg1s[F1], wg2s[F1*F2], bg2s[F2];

    const int bt = blockIdx.x, tid = threadIdx.x;
    const long eb = (long)bt * EE;

    for (int v = tid; v < NN; v += 256) {
        xs[v] = nf[(long)bt*NN + v];
        dinv[v] = 1.0f;
        agg1[v] = 0.f;
    }
    for (int i = tid; i < NN*F1; i += 256) agg2[i] = 0.f;
    if (tid < F1) { wg1s[tid] = Wg1[tid]; bg1s[tid] = bg1[tid]; }
    if (tid < F2) bg2s[tid] = bg2[tid];
    for (int i = tid; i < F1*F2; i += 256) wg2s[i] = Wg2[i];
    __syncthreads();

    for (int e = tid; e < EE; e += 256)
        atomicAdd(&dinv[edst[eb+e]], ew[eb+e]);
    __syncthreads();
    for (int v = tid; v < NN; v += 256) {
        float dg = dinv[v];
        dinv[v] = dg > 0.f ? 1.0f / sqrtf(fmaxf(dg, 1e-12f)) : 0.f;
    }
    __syncthreads();

    for (int e = tid; e < EE; e += 256) {
        int s = esrc[eb+e], d = edst[eb+e];
        float nm = dinv[s] * ew[eb+e] * dinv[d];
        nrm[e] = nm;
        atomicAdd(&agg1[d], nm * xs[s]);
    }
    __syncthreads();
    for (int v = tid; v < NN; v += 256) agg1[v] += dinv[v]*dinv[v]*xs[v];
    __syncthreads();
    for (int i = tid; i < NN*F1; i += 256) {
        int v = i / F1, f = i - v*F1;
        x1[i] = relu_(agg1[v] * wg1s[f] + bg1s[f]);
    }
    __syncthreads();

    for (int e = tid; e < EE; e += 256) {
        int s = esrc[eb+e], d = edst[eb+e];
        float nm = nrm[e];
        #pragma unroll
        for (int f = 0; f < F1; ++f)
            atomicAdd(&agg2[d*F1+f], nm * x1[s*F1+f]);
    }
    __syncthreads();
    for (int i = tid; i < NN*F1; i += 256) {
        int v = i / F1;
        agg2[i] += dinv[v]*dinv[v]*x1[i];
    }
    __syncthreads();

    for (int i = tid; i < NN*F2; i += 256) {
        int v = i >> 5, k = i & 31;
        float o = bg2s[k];
        #pragma unroll
        for (int f = 0; f < F1; ++f) o += agg2[v*F1+f] * wg2s[f*F2+k];
        x2g[(long)bt*K2 + i] = __float2bfloat16(relu_(o));
    }
}

// ---------------- transpose-pack Wgfc fp32 [13600,128] -> bf16 [128,13600] --
__global__ __launch_bounds__(256) void packT_kernel(
    const float* __restrict__ W, __hip_bfloat16* __restrict__ out)
{
    __shared__ float tile[64][129];
    const int k0 = blockIdx.x * 64, tid = threadIdx.x;
    for (int i = tid; i < 64*128; i += 256) {
        int r = i >> 7, j = i & 127;
        tile[r][j] = (k0 + r < K2) ? W[(size_t)(k0+r)*II + j] : 0.f;
    }
    __syncthreads();
    for (int i = tid; i < 64*128; i += 256) {
        int j = i >> 6, r = i & 63;
        if (k0 + r < K2) out[(size_t)j*K2 + k0 + r] = __float2bfloat16(tile[r][j]);
    }
}

// ---------------- MFMA bf16 GEMM, split-K: g_pre += x2 @ Wgfc ---------------
#define GBM 64
#define GBK 64
#define GCH 8
#define GST 27
__global__ __launch_bounds__(256) void gemm_kernel(
    const __hip_bfloat16* __restrict__ A, const __hip_bfloat16* __restrict__ Bt,
    float* __restrict__ C)
{
    __shared__ __align__(16) char As[2][GBM*GBK*2];
    __shared__ __align__(16) char Bs[2][II*GBK*2];
    const int tid = threadIdx.x;
    const int row0 = blockIdx.x * GBM;
    const int kbeg = blockIdx.y * (GST*GBK);
    const int wave = tid >> 6, lane = tid & 63;
    const int wm = wave >> 1, wn = wave & 1;
    const int l16 = lane & 15, lk = lane >> 4;
    const short* Aa = (const short*)A;
    const short* Bb = (const short*)Bt;

    const int ar = tid >> 2, ac = tid & 3;
    const int bc = tid >> 1, bh = (tid & 1) * 4;

    f32x4 acc[2][4];
    #pragma unroll
    for (int m = 0; m < 2; ++m)
        #pragma unroll
        for (int n = 0; n < 4; ++n) acc[m][n] = (f32x4){0.f,0.f,0.f,0.f};

    {
        #pragma unroll
        for (int j = 0; j < 2; ++j) {
            bf16x8 va = {0,0,0,0,0,0,0,0};
            int k = kbeg + ac*16 + j*8;
            if (k < K2) va = *(const bf16x8*)(Aa + (size_t)(row0+ar)*K2 + k);
            *(bf16x8*)(&As[0][0] + ((ar*128 + (ac*2+j)*16) ^ ((ar&7)<<4))) = va;
        }
        #pragma unroll
        for (int j = 0; j < 4; ++j) {
            bf16x8 vb = {0,0,0,0,0,0,0,0};
            int k = kbeg + (bh+j)*8;
            if (k < K2) vb = *(const bf16x8*)(Bb + (size_t)bc*K2 + k);
            *(bf16x8*)(&Bs[0][0] + ((bc*128 + (bh+j)*16) ^ ((bc&7)<<4))) = vb;
        }
    }
    __syncthreads();

    for (int s = 0; s < GST; ++s) {
        const int d = s & 1;
        bf16x8 pa[2], pb[4];
        #pragma unroll
        for (int j = 0; j < 2; ++j) pa[j] = (bf16x8){0,0,0,0,0,0,0,0};
        #pragma unroll
        for (int j = 0; j < 4; ++j) pb[j] = (bf16x8){0,0,0,0,0,0,0,0};
        if (s + 1 < GST) {
            int k0n = kbeg + (s+1)*GBK;
            #pragma unroll
            for (int j = 0; j < 2; ++j) {
                int k = k0n + ac*16 + j*8;
                if (k < K2) pa[j] = *(const bf16x8*)(Aa + (size_t)(row0+ar)*K2 + k);
            }
            #pragma unroll
            for (int j = 0; j < 4; ++j) {
                int k = k0n + (bh+j)*8;
                if (k < K2) pb[j] = *(const bf16x8*)(Bb + (size_t)bc*K2 + k);
            }
        }
        #pragma unroll
        for (int s2 = 0; s2 < 2; ++s2) {
            bf16x8 af[2], bf[4];
            #pragma unroll
            for (int m = 0; m < 2; ++m) {
                int row = wm*32 + m*16 + l16;
                af[m] = *(const bf16x8*)(&As[d][0] + ((row*128 + s2*64 + lk*16) ^ ((row&7)<<4)));
            }
            #pragma unroll
            for (int n = 0; n < 4; ++n) {
                int col = wn*64 + n*16 + l16;
                bf[n] = *(const bf16x8*)(&Bs[d][0] + ((col*128 + s2*64 + lk*16) ^ ((col&7)<<4)));
            }
            #pragma unroll
            for (int m = 0; m < 2; ++m)
                #pragma unroll
                for (int n = 0; n < 4; ++n)
                    acc[m][n] = __builtin_amdgcn_mfma_f32_16x16x32_bf16(af[m], bf[n], acc[m][n], 0, 0, 0);
        }
        if (s + 1 < GST) {
            #pragma unroll
            for (int j = 0; j < 2; ++j)
                *(bf16x8*)(&As[d^1][0] + ((ar*128 + (ac*2+j)*16) ^ ((ar&7)<<4))) = pa[j];
            #pragma unroll
            for (int j = 0; j < 4; ++j)
                *(bf16x8*)(&Bs[d^1][0] + ((bc*128 + (bh+j)*16) ^ ((bc&7)<<4))) = pb[j];
        }
        __syncthreads();
    }

    #pragma unroll
    for (int m = 0; m < 2; ++m)
        #pragma unroll
        for (int n = 0; n < 4; ++n)
            #pragma unroll
            for (int q = 0; q < 4; ++q)
                atomicAdd(&C[(size_t)(row0 + wm*32 + m*16 + lk*4 + q)*II + wn*64 + n*16 + l16],
                          acc[m][n][q]);
}

// ---------------- infect & temp MLP branches (16 rows per block) ------------
__global__ __launch_bounds__(256) void branches_kernel(
    const float* __restrict__ infect, const float* __restrict__ temp,
    const float* __restrict__ Wi1, const float* __restrict__ bi1,
    const float* __restrict__ Wi2, const float* __restrict__ bi2,
    const float* __restrict__ Wi3, const float* __restrict__ bi3,
    const float* __restrict__ Wi4, const float* __restrict__ bi4,
    const float* __restrict__ Wt1, const float* __restrict__ bt1,
    const float* __restrict__ Wt2, const float* __restrict__ bt2,
    float* __restrict__ infout, float* __restrict__ tpout)
{
    __shared__ float inA[16*25], inT[16*13];
    __shared__ float bufA[16*II], bufB[16*II];
    const int r0 = blockIdx.x * 16, tid = threadIdx.x;

    for (int i = tid; i < 16*25; i += 256) { int r=i/25,k=i-r*25; inA[i] = infect[(long)(r0+r)*25+k]; }
    for (int i = tid; i < 16*13; i += 256) { int r=i/13,k=i-r*13; inT[i] = temp[(long)(r0+r)*13+k]; }
    __syncthreads();
    for (int i = tid; i < 16*II; i += 256) { int r=i>>7,u=i&127; float o=bi1[u];
        for (int k=0;k<25;++k) o += inA[r*25+k]*Wi1[k*II+u];
        bufA[i]=relu_(o); }
    __syncthreads();
    for (int i = tid; i < 16*II; i += 256) { int r=i>>7,u=i&127; float o=bi2[u];
        for (int k=0;k<II;++k) o += bufA[r*II+k]*Wi2[k*II+u];
        bufB[i]=relu_(o); }
    __syncthreads();
    for (int i = tid; i < 16*64; i += 256) { int r=i>>6,u=i&63; float o=bi3[u];
        for (int k=0;k<II;++k) o += bufB[r*II+k]*Wi3[k*64+u];
        bufA[r*64+u]=relu_(o); }
    __syncthreads();
    for (int i = tid; i < 16*II; i += 256) { int r=i>>7,u=i&127; float o=bi4[u];
        for (int k=0;k<64;++k) o += bufA[r*64+k]*Wi4[k*II+u];
        infout[(long)(r0+r)*II+u]=relu_(o); }
    for (int i = tid; i < 16*64; i += 256) { int r=i>>6,u=i&63; float o=bt1[u];
        for (int k=0;k<13;++k) o += inT[r*13+k]*Wt1[k*64+u];
        bufB[r*64+u]=relu_(o); }
    __syncthreads();
    for (int i = tid; i < 16*II; i += 256) { int r=i>>7,u=i&127; float o=bt2[u];
        for (int k=0;k<64;++k) o += bufB[r*64+k]*Wt2[k*II+u];
        tpout[(long)(r0+r)*II+u]=relu_(o); }
}

// ---- li = relu(cat@Wcat+bcat); xg4 = li@Wih^T + bih + bhh, per-unit packed -
// xg4 layout: [bt][unit(256)][gate(4)] floats (gate order i,f,g,o)
__global__ __launch_bounds__(256) void li_xg_kernel(
    const float* __restrict__ g_pre, const float* __restrict__ bgfc,
    const float* __restrict__ infb, const float* __restrict__ tpb,
    const float* __restrict__ Wcat, const float* __restrict__ bcat,
    const float* __restrict__ Wih, const float* __restrict__ bih,
    const float* __restrict__ bhh, float* __restrict__ xg4)
{
    __shared__ float cat[16*384];
    __shared__ __align__(16) float li[16*II];
    const int r0 = blockIdx.x * 16, tid = threadIdx.x;

    for (int i = tid; i < 16*II; i += 256) {
        int r = i>>7, u = i&127;
        cat[r*384 + u]       = relu_(g_pre[(long)(r0+r)*II+u] + bgfc[u]);
        cat[r*384 + 128 + u] = infb[(long)(r0+r)*II+u];
        cat[r*384 + 256 + u] = tpb[(long)(r0+r)*II+u];
    }
    __syncthreads();
    {
        int u = tid & 127, rh = tid >> 7;
        float acc[8];
        #pragma unroll
        for (int x = 0; x < 8; ++x) acc[x] = bcat[u];
        for (int k = 0; k < 384; ++k) {
            float w = Wcat[k*II+u];
            #pragma unroll
            for (int x = 0; x < 8; ++x) acc[x] += cat[(rh*8+x)*384 + k] * w;
        }
        #pragma unroll
        for (int x = 0; x < 8; ++x) li[(rh*8+x)*II + u] = relu_(acc[x]);
    }
    __syncthreads();
    for (int jj = 0; jj < 4; ++jj) {           // jj = gate index (i,f,g,o)
        int j = tid + jj*256;                  // Wih row = gate*256 + unit
        float bb = bih[j] + bhh[j];
        float acc[16];
        #pragma unroll
        for (int r = 0; r < 16; ++r) acc[r] = bb;
        for (int k4 = 0; k4 < 32; ++k4) {
            float4 wv = *(const float4*)&Wih[(long)j*II + k4*4];
            #pragma unroll
            for (int r = 0; r < 16; ++r) {
                float4 lv = *(const float4*)&li[r*II + k4*4];
                acc[r] += wv.x*lv.x + wv.y*lv.y + wv.z*lv.z + wv.w*lv.w;
            }
        }
        #pragma unroll
        for (int r = 0; r < 16; ++r)
            xg4[(long)(r0+r)*1024 + tid*4 + jj] = acc[r];
    }
}

// ---------------- pack Whh fp32 -> fp16 MFMA B-fragments --------------------
// REG fidx: j<5 -> j*8+kc (40); j==7,kc<6 -> 40+kc (6).  LDS fidx: j==5 -> kc;
// j==6 -> 8+kc; j==7,kc>=6 -> 16+(kc-6).
// frag lane l: row=(j>>1)*256 + 32w + (j&1)*16 + (l&15), k=32kc+8(l>>4)..+8
__global__ __launch_bounds__(256) void pack_whh_kernel(
    const float* __restrict__ Whh, h8* __restrict__ bregp,
    h8* __restrict__ bldsp)
{
    int i = blockIdx.x*256 + threadIdx.x;    // 128 blocks -> 32768 = 23552+9216
    int w, j, kc, lane;
    bool isreg = (i < BREG_N);
    if (isreg) {
        w = i / (BREG_PW*64); int r = i % (BREG_PW*64);
        int fidx = r >> 6; lane = r & 63;
        if (fidx < 40) { j = fidx >> 3; kc = fidx & 7; }
        else           { j = 7;        kc = fidx - 40; }
    } else {
        int L = i - BREG_N;
        if (L >= BLDS_N) return;
        w = L / (BLDS_PW*64); int r = L % (BLDS_PW*64);
        int fidx = r >> 6; lane = r & 63;
        if (fidx < 8)       { j = 5; kc = fidx; }
        else if (fidx < 16) { j = 6; kc = fidx - 8; }
        else                { j = 7; kc = 6 + (fidx - 16); }
    }
    int row = (j >> 1)*256 + 32*w + (j & 1)*16 + (lane & 15);
    int col = 32*kc + 8*(lane >> 4);
    h8 v;
    #pragma unroll
    for (int e = 0; e < 8; ++e) v[e] = (_Float16)Whh[(long)row*HH + col + e];
    if (isreg) bregp[i] = v; else bldsp[i - BREG_N] = v;
}

// ---------------- LSTM: 1 block/batch, AGPR-fed MFMA, 1 barrier/step --------
__attribute__((amdgpu_waves_per_eu(2, 2)))
__global__ __launch_bounds__(512) void lstm_kernel(
    const float* __restrict__ xg4, const h8* __restrict__ bregp,
    const h8* __restrict__ bldsp, const float* __restrict__ h0,
    const float* __restrict__ c0, float* __restrict__ hbuf)
{
    const int u = threadIdx.x;
    const int lane = u & 63;
    const int w = u >> 6;
    const int b = blockIdx.x;
    const int l15 = lane & 15;
    const int n0 = 32*w + l15;           // lanes<16: first owned unit

    __shared__ __align__(16) h8 wlds[BLDS_N];          // 144 KB
    __shared__ __align__(16) _Float16 harr[2][HH];     // 1 KB

    for (int i = u; i < BLDS_N; i += 512) wlds[i] = bldsp[i];

    h8 bfr[BREG_PW];                                   // 46 frags -> AGPR
    {
        const h8* bp = bregp + (size_t)(w*BREG_PW)*64 + lane;
        #pragma unroll
        for (int m = 0; m < BREG_PW; ++m) bfr[m] = bp[(size_t)m*64];
    }

    float c0r = 0.f, c1r = 0.f, h0l = 0.f, h1l = 0.f;
    if (lane < 16) { c0r = c0[b*HH + n0]; c1r = c0[b*HH + n0 + 16]; }
    if (u < 256) harr[0][u] = (_Float16)h0[b*HH + u];
    __syncthreads();

    const float4* xb4 = (const float4*)xg4 + (size_t)b*TT*256;
    const char* hbase = (const char*)harr;
    const int q16 = (lane >> 4) << 4;

    #pragma unroll 1
    for (int t = 0; t < TT; ++t) {
        const int cb = t & 1;
        float4 xa = {0,0,0,0}, xb = {0,0,0,0};
        if (lane < 16) {
            xa = xb4[(size_t)t*256 + n0];
            xb = xb4[(size_t)t*256 + n0 + 16];
        }
        f32x4 acc[8];
        #pragma unroll
        for (int j = 0; j < 8; ++j) acc[j] = (f32x4){0.f,0.f,0.f,0.f};

        h8 a_cur = *(const h8*)(hbase + cb*512 + q16);
        asm volatile("s_nop 1" ::: );          // VALU->MFMA SrcC hazard
        #pragma unroll
        for (int kc = 0; kc < 8; ++kc) {
            h8 a_nxt = a_cur;
            if (kc < 7)
                a_nxt = *(const h8*)(hbase + cb*512 + (kc+1)*64 + q16);
            h8 b5 = wlds[(size_t)(w*BLDS_PW + kc)*64 + lane];
            h8 b6 = wlds[(size_t)(w*BLDS_PW + 8 + kc)*64 + lane];
            MFMA_AG(acc[0], a_cur, bfr[0*8 + kc]);
            MFMA_AG(acc[1], a_cur, bfr[1*8 + kc]);
            MFMA_AG(acc[2], a_cur, bfr[2*8 + kc]);
            MFMA_AG(acc[3], a_cur, bfr[3*8 + kc]);
            MFMA_AG(acc[4], a_cur, bfr[4*8 + kc]);
            MFMA_VG(acc[5], a_cur, b5);
            MFMA_VG(acc[6], a_cur, b6);
            if (kc < 6) {
                MFMA_AG(acc[7], a_cur, bfr[40 + kc]);
            } else {
                h8 b7 = wlds[(size_t)(w*BLDS_PW + 16 + (kc-6))*64 + lane];
                MFMA_VG(acc[7], a_cur, b7);
            }
            a_cur = a_nxt;
        }
        asm volatile("s_nop 7\ns_nop 7" ::: ); // MFMA->VALU acc-read hazard

        if (lane < 16) {
            float gi0 = acc[0][0] + xa.x, gf0 = acc[2][0] + xa.y;
            float gg0 = acc[4][0] + xa.z, go0 = acc[6][0] + xa.w;
            float gi1 = acc[1][0] + xb.x, gf1 = acc[3][0] + xb.y;
            float gg1 = acc[5][0] + xb.z, go1 = acc[7][0] + xb.w;
            c0r = sigmoid_(gf0)*c0r + sigmoid_(gi0)*tanhf(gg0);
            h0l = sigmoid_(go0)*tanhf(c0r);
            c1r = sigmoid_(gf1)*c1r + sigmoid_(gi1)*tanhf(gg1);
            h1l = sigmoid_(go1)*tanhf(c1r);
            harr[cb ^ 1][n0]      = (_Float16)h0l;
            harr[cb ^ 1][n0 + 16] = (_Float16)h1l;
        }
        __syncthreads();
    }
    if (lane < 16) {
        hbuf[b*HH + n0]      = h0l;
        hbuf[b*HH + n0 + 16] = h1l;
    }
}

// ---------------- final FC: out = relu(relu(h_T) @ Wfc + bfc) ---------------
__global__ __launch_bounds__(256) void final_fc_kernel(
    const float* __restrict__ hbuf, const float* __restrict__ Wfc,
    const float* __restrict__ bfc, float* __restrict__ out)
{
    int idx = blockIdx.x*256 + threadIdx.x;
    if (idx >= BB*N2) return;
    int b = idx / N2, j = idx - b*N2;
    const float* h = hbuf + b*HH;
    float o = bfc[j];
    for (int k = 0; k < HH; ++k) o += fmaxf(h[k], 0.f) * Wfc[(long)k*N2 + j];
    out[idx] = relu_(o);
}

extern "C" void kernel_launch(void* const* d_in, const int* in_sizes, int n_in,
                              void* d_out, int out_size, void* d_ws, size_t ws_size,
                              hipStream_t stream) {
    const float* nf     = (const float*)d_in[0];
    const int*   esrc   = (const int*)d_in[1];
    const int*   edst   = (const int*)d_in[2];
    const float* ew     = (const float*)d_in[3];
    const float* infect = (const float*)d_in[4];
    const float* temp   = (const float*)d_in[5];
    const float* h0     = (const float*)d_in[6];
    const float* c0     = (const float*)d_in[7];
    const float* Wg1    = (const float*)d_in[8];
    const float* bg1    = (const float*)d_in[9];
    const float* Wg2    = (const float*)d_in[10];
    const float* bg2    = (const float*)d_in[11];
    const float* Wgfc   = (const float*)d_in[12];
    const float* bgfc   = (const float*)d_in[13];
    const float* Wi1    = (const float*)d_in[14];
    const float* bi1    = (const float*)d_in[15];
    const float* Wi2    = (const float*)d_in[16];
    const float* bi2    = (const float*)d_in[17];
    const float* Wi3    = (const float*)d_in[18];
    const float* bi3    = (const float*)d_in[19];
    const float* Wi4    = (const float*)d_in[20];
    const float* bi4    = (const float*)d_in[21];
    const float* Wt1    = (const float*)d_in[22];
    const float* bt1    = (const float*)d_in[23];
    const float* Wt2    = (const float*)d_in[24];
    const float* bt2    = (const float*)d_in[25];
    const float* Wcat   = (const float*)d_in[26];
    const float* bcat   = (const float*)d_in[27];
    const float* Wih    = (const float*)d_in[28];
    const float* Whh    = (const float*)d_in[29];
    const float* bih    = (const float*)d_in[30];
    const float* bhh    = (const float*)d_in[31];
    const float* Wfc    = (const float*)d_in[32];
    const float* bfc    = (const float*)d_in[33];

    char* ws = (char*)d_ws;
    size_t off = 0;
    __hip_bfloat16* x2g = (__hip_bfloat16*)(ws + off); off += (size_t)BT*K2*2;
    __hip_bfloat16* WgfcT = (__hip_bfloat16*)(ws + off); off += (size_t)II*K2*2;
    float* g_pre = (float*)(ws + off); off += (size_t)BT*II*4;
    float* infb  = (float*)(ws + off); off += (size_t)BT*II*4;
    float* tpb   = (float*)(ws + off); off += (size_t)BT*II*4;
    float* xg4   = (float*)(ws + off); off += (size_t)BT*1024*4;
    float* hbuf  = (float*)(ws + off); off += (size_t)BB*HH*4;
    h8* bregp = (h8*)(ws + off); off += (size_t)BREG_N*16;
    h8* bldsp = (h8*)(ws + off); off += (size_t)BLDS_N*16;

    hipMemsetAsync(g_pre, 0, (size_t)BT*II*4, stream);

    pack_whh_kernel<<<128, 256, 0, stream>>>(Whh, bregp, bldsp);
    packT_kernel<<<(K2 + 63)/64, 256, 0, stream>>>(Wgfc, WgfcT);
    gcn_kernel<<<BT, 256, 0, stream>>>(nf, esrc, edst, ew, Wg1, bg1, Wg2, bg2, x2g);
    branches_kernel<<<BT/16, 256, 0, stream>>>(infect, temp, Wi1, bi1, Wi2, bi2,
                                               Wi3, bi3, Wi4, bi4, Wt1, bt1, Wt2, bt2,
                                               infb, tpb);
    gemm_kernel<<<dim3(BT/GBM, GCH), 256, 0, stream>>>(x2g, WgfcT, g_pre);
    li_xg_kernel<<<BT/16, 256, 0, stream>>>(g_pre, bgfc, infb, tpb, Wcat, bcat,
                                            Wih, bih, bhh, xg4);
    lstm_kernel<<<BB, 512, 0, stream>>>(xg4, bregp, bldsp, h0, c0, hbuf);
    final_fc_kernel<<<(BB*N2 + 255)/256, 256, 0, stream>>>(hbuf, Wfc, bfc, (float*)d_out);
}

// Round 10
// 674.587 us; speedup vs baseline: 1.1601x; 1.1601x over previous
//
#include <hip/hip_runtime.h>
#include <hip/hip_bf16.h>

#define BB 8
#define TT 168
#define NN 425
#define EE 2048
#define II 128
#define HH 256
#define F1 10
#define F2 32
#define BT (BB*TT)       // 1344
#define K2 (NN*F2)       // 13600
#define N2 (2*NN)        // 850

// MFMA LSTM fragment bookkeeping (round-8 verified):
#define BREG_PW 46
#define BLDS_PW 18
#define BREG_N (8*BREG_PW*64)   // 23552 h8
#define BLDS_N (8*BLDS_PW*64)   // 9216 h8 = 144 KB

// blx fragment table: 444 frags total
#define FR_TOTAL 444

typedef _Float16 h2 __attribute__((ext_vector_type(2)));
typedef _Float16 h8 __attribute__((ext_vector_type(8)));
typedef short bf16x8 __attribute__((ext_vector_type(8)));
typedef float f32x4 __attribute__((ext_vector_type(4)));

__device__ __forceinline__ float relu_(float x){ return fmaxf(x, 0.f); }
__device__ __forceinline__ float sigmoid_(float x){ return 1.f/(1.f + expf(-x)); }

#define MFMA16(ACC, AV, BV) \
    ACC = __builtin_amdgcn_mfma_f32_16x16x32_f16((AV), (BV), (ACC), 0, 0, 0)

// swizzled fp16 activation LDS helpers (convention verified by passing gemm)
__device__ __forceinline__ h8 actld(const char* act, int K, int lane, int kc){
    int row = lane & 15;
    unsigned off = ((unsigned)(row*K + kc*32 + ((lane>>4)<<3))*2) ^ (unsigned)((row&7)<<4);
    return *(const h8*)(act + off);
}
__device__ __forceinline__ void actst(char* act, int K, int row, int col, _Float16 v){
    unsigned off = ((unsigned)(row*K + col)*2) ^ (unsigned)((row&7)<<4);
    *(_Float16*)(act + off) = v;
}

// ---------------- GCN: two layers fused, one block per (b,t) graph ----------
__global__ __launch_bounds__(256) void gcn_kernel(
    const float* __restrict__ nf, const int* __restrict__ esrc,
    const int* __restrict__ edst, const float* __restrict__ ew,
    const float* __restrict__ Wg1, const float* __restrict__ bg1,
    const float* __restrict__ Wg2, const float* __restrict__ bg2,
    __hip_bfloat16* __restrict__ x2g)
{
    __shared__ float xs[NN];
    __shared__ float dinv[NN];
    __shared__ float agg1[NN];
    __shared__ float nrm[EE];
    __shared__ float x1[NN*F1];
    __shared__ float agg2[NN*F1];
    __shared__ float wg1s[F1], bg1s[F1], wg2s[F1*F2], bg2s[F2];

    const int bt = blockIdx.x, tid = threadIdx.x;
    const long eb = (long)bt * EE;

    for (int v = tid; v < NN; v += 256) {
        xs[v] = nf[(long)bt*NN + v];
        dinv[v] = 1.0f;
        agg1[v] = 0.f;
    }
    for (int i = tid; i < NN*F1; i += 256) agg2[i] = 0.f;
    if (tid < F1) { wg1s[tid] = Wg1[tid]; bg1s[tid] = bg1[tid]; }
    if (tid < F2) bg2s[tid] = bg2[tid];
    for (int i = tid; i < F1*F2; i += 256) wg2s[i] = Wg2[i];
    __syncthreads();

    for (int e = tid; e < EE; e += 256)
        atomicAdd(&dinv[edst[eb+e]], ew[eb+e]);
    __syncthreads();
    for (int v = tid; v < NN; v += 256) {
        float dg = dinv[v];
        dinv[v] = dg > 0.f ? 1.0f / sqrtf(fmaxf(dg, 1e-12f)) : 0.f;
    }
    __syncthreads();

    for (int e = tid; e < EE; e += 256) {
        int s = esrc[eb+e], d = edst[eb+e];
        float nm = dinv[s] * ew[eb+e] * dinv[d];
        nrm[e] = nm;
        atomicAdd(&agg1[d], nm * xs[s]);
    }
    __syncthreads();
    for (int v = tid; v < NN; v += 256) agg1[v] += dinv[v]*dinv[v]*xs[v];
    __syncthreads();
    for (int i = tid; i < NN*F1; i += 256) {
        int v = i / F1, f = i - v*F1;
        x1[i] = relu_(agg1[v] * wg1s[f] + bg1s[f]);
    }
    __syncthreads();

    for (int e = tid; e < EE; e += 256) {
        int s = esrc[eb+e], d = edst[eb+e];
        float nm = nrm[e];
        #pragma unroll
        for (int f = 0; f < F1; ++f)
            atomicAdd(&agg2[d*F1+f], nm * x1[s*F1+f]);
    }
    __syncthreads();
    for (int i = tid; i < NN*F1; i += 256) {
        int v = i / F1;
        agg2[i] += dinv[v]*dinv[v]*x1[i];
    }
    __syncthreads();

    for (int i = tid; i < NN*F2; i += 256) {
        int v = i >> 5, k = i & 31;
        float o = bg2s[k];
        #pragma unroll
        for (int f = 0; f < F1; ++f) o += agg2[v*F1+f] * wg2s[f*F2+k];
        x2g[(long)bt*K2 + i] = __float2bfloat16(relu_(o));
    }
}

// ---------------- transpose-pack Wgfc fp32 [13600,128] -> bf16 [128,13600] --
__global__ __launch_bounds__(256) void packT_kernel(
    const float* __restrict__ W, __hip_bfloat16* __restrict__ out)
{
    __shared__ float tile[64][129];
    const int k0 = blockIdx.x * 64, tid = threadIdx.x;
    for (int i = tid; i < 64*128; i += 256) {
        int r = i >> 7, j = i & 127;
        tile[r][j] = (k0 + r < K2) ? W[(size_t)(k0+r)*II + j] : 0.f;
    }
    __syncthreads();
    for (int i = tid; i < 64*128; i += 256) {
        int j = i >> 6, r = i & 63;
        if (k0 + r < K2) out[(size_t)j*K2 + k0 + r] = __float2bfloat16(tile[r][j]);
    }
}

// ---------------- MFMA bf16 GEMM, split-K: g_pre += x2 @ Wgfc ---------------
#define GBM 64
#define GBK 64
#define GCH 8
#define GST 27
__global__ __launch_bounds__(256) void gemm_kernel(
    const __hip_bfloat16* __restrict__ A, const __hip_bfloat16* __restrict__ Bt,
    float* __restrict__ C)
{
    __shared__ __align__(16) char As[2][GBM*GBK*2];
    __shared__ __align__(16) char Bs[2][II*GBK*2];
    const int tid = threadIdx.x;
    const int row0 = blockIdx.x * GBM;
    const int kbeg = blockIdx.y * (GST*GBK);
    const int wave = tid >> 6, lane = tid & 63;
    const int wm = wave >> 1, wn = wave & 1;
    const int l16 = lane & 15, lk = lane >> 4;
    const short* Aa = (const short*)A;
    const short* Bb = (const short*)Bt;

    const int ar = tid >> 2, ac = tid & 3;
    const int bc = tid >> 1, bh = (tid & 1) * 4;

    f32x4 acc[2][4];
    #pragma unroll
    for (int m = 0; m < 2; ++m)
        #pragma unroll
        for (int n = 0; n < 4; ++n) acc[m][n] = (f32x4){0.f,0.f,0.f,0.f};

    {
        #pragma unroll
        for (int j = 0; j < 2; ++j) {
            bf16x8 va = {0,0,0,0,0,0,0,0};
            int k = kbeg + ac*16 + j*8;
            if (k < K2) va = *(const bf16x8*)(Aa + (size_t)(row0+ar)*K2 + k);
            *(bf16x8*)(&As[0][0] + ((ar*128 + (ac*2+j)*16) ^ ((ar&7)<<4))) = va;
        }
        #pragma unroll
        for (int j = 0; j < 4; ++j) {
            bf16x8 vb = {0,0,0,0,0,0,0,0};
            int k = kbeg + (bh+j)*8;
            if (k < K2) vb = *(const bf16x8*)(Bb + (size_t)bc*K2 + k);
            *(bf16x8*)(&Bs[0][0] + ((bc*128 + (bh+j)*16) ^ ((bc&7)<<4))) = vb;
        }
    }
    __syncthreads();

    for (int s = 0; s < GST; ++s) {
        const int d = s & 1;
        bf16x8 pa[2], pb[4];
        #pragma unroll
        for (int j = 0; j < 2; ++j) pa[j] = (bf16x8){0,0,0,0,0,0,0,0};
        #pragma unroll
        for (int j = 0; j < 4; ++j) pb[j] = (bf16x8){0,0,0,0,0,0,0,0};
        if (s + 1 < GST) {
            int k0n = kbeg + (s+1)*GBK;
            #pragma unroll
            for (int j = 0; j < 2; ++j) {
                int k = k0n + ac*16 + j*8;
                if (k < K2) pa[j] = *(const bf16x8*)(Aa + (size_t)(row0+ar)*K2 + k);
            }
            #pragma unroll
            for (int j = 0; j < 4; ++j) {
                int k = k0n + (bh+j)*8;
                if (k < K2) pb[j] = *(const bf16x8*)(Bb + (size_t)bc*K2 + k);
            }
        }
        #pragma unroll
        for (int s2 = 0; s2 < 2; ++s2) {
            bf16x8 af[2], bf[4];
            #pragma unroll
            for (int m = 0; m < 2; ++m) {
                int row = wm*32 + m*16 + l16;
                af[m] = *(const bf16x8*)(&As[d][0] + ((row*128 + s2*64 + lk*16) ^ ((row&7)<<4)));
            }
            #pragma unroll
            for (int n = 0; n < 4; ++n) {
                int col = wn*64 + n*16 + l16;
                bf[n] = *(const bf16x8*)(&Bs[d][0] + ((col*128 + s2*64 + lk*16) ^ ((col&7)<<4)));
            }
            #pragma unroll
            for (int m = 0; m < 2; ++m)
                #pragma unroll
                for (int n = 0; n < 4; ++n)
                    acc[m][n] = __builtin_amdgcn_mfma_f32_16x16x32_bf16(af[m], bf[n], acc[m][n], 0, 0, 0);
        }
        if (s + 1 < GST) {
            #pragma unroll
            for (int j = 0; j < 2; ++j)
                *(bf16x8*)(&As[d^1][0] + ((ar*128 + (ac*2+j)*16) ^ ((ar&7)<<4))) = pa[j];
            #pragma unroll
            for (int j = 0; j < 4; ++j)
                *(bf16x8*)(&Bs[d^1][0] + ((bc*128 + (bh+j)*16) ^ ((bc&7)<<4))) = pb[j];
        }
        __syncthreads();
    }

    #pragma unroll
    for (int m = 0; m < 2; ++m)
        #pragma unroll
        for (int n = 0; n < 4; ++n)
            #pragma unroll
            for (int q = 0; q < 4; ++q)
                atomicAdd(&C[(size_t)(row0 + wm*32 + m*16 + lk*4 + q)*II + wn*64 + n*16 + l16],
                          acc[m][n][q]);
}

// ---------------- pack branch/cat/ih weights into MFMA B-fragments ----------
// frag(nt,kc) lane l: n = nt*16+(l&15), k = kc*32+8*(l>>4)+e; val = S[n*sn+k*sk]
// table: Wi1[0,8) Wi2[8,40) Wi3[40,56) Wi4[56,72) Wt1[72,76) Wt2[76,92)
//        Wcat[92,188) Wih[188,444)
__global__ __launch_bounds__(64) void pack_frags_kernel(
    const float* __restrict__ Wi1, const float* __restrict__ Wi2,
    const float* __restrict__ Wi3, const float* __restrict__ Wi4,
    const float* __restrict__ Wt1, const float* __restrict__ Wt2,
    const float* __restrict__ Wcat, const float* __restrict__ Wih,
    h8* __restrict__ out)
{
    int f = blockIdx.x, l = threadIdx.x;
    const float* S; int sn, sk, K, KC, base;
    if      (f < 8)   { S=Wi1;  sn=1;   sk=128; K=25;  KC=1;  base=0;  }
    else if (f < 40)  { S=Wi2;  sn=1;   sk=128; K=128; KC=4;  base=8;  }
    else if (f < 56)  { S=Wi3;  sn=1;   sk=64;  K=128; KC=4;  base=40; }
    else if (f < 72)  { S=Wi4;  sn=1;   sk=128; K=64;  KC=2;  base=56; }
    else if (f < 76)  { S=Wt1;  sn=1;   sk=64;  K=13;  KC=1;  base=72; }
    else if (f < 92)  { S=Wt2;  sn=1;   sk=128; K=64;  KC=2;  base=76; }
    else if (f < 188) { S=Wcat; sn=1;   sk=128; K=384; KC=12; base=92; }
    else              { S=Wih;  sn=128; sk=1;   K=128; KC=4;  base=188;}
    int loc = f - base, nt = loc / KC, kc = loc % KC;
    int n = nt*16 + (l & 15);
    int k0 = kc*32 + ((l >> 4) << 3);
    h8 v;
    #pragma unroll
    for (int e = 0; e < 8; ++e) {
        int k = k0 + e;
        v[e] = (_Float16)((k < K) ? S[(size_t)n*sn + (size_t)k*sk] : 0.f);
    }
    out[(size_t)f*64 + l] = v;
}

// ------- fused branches + concat + li + xg, all MFMA (16 bt-rows/block) -----
__global__ __launch_bounds__(256) void blx_kernel(
    const float* __restrict__ infect, const float* __restrict__ temp,
    const float* __restrict__ g_pre, const float* __restrict__ bgfc,
    const float* __restrict__ bi1, const float* __restrict__ bi2,
    const float* __restrict__ bi3, const float* __restrict__ bi4,
    const float* __restrict__ bt1, const float* __restrict__ bt2,
    const float* __restrict__ bcat, const float* __restrict__ bih,
    const float* __restrict__ bhh, const h8* __restrict__ frags,
    float* __restrict__ xg)
{
    __shared__ __align__(16) char CAT[16*384*2];   // 12 KB [g|inf|tp]
    __shared__ __align__(16) char S0[16*128*2];    // 4 KB
    __shared__ __align__(16) char S1[16*128*2];    // 4 KB
    __shared__ __align__(16) char LIb[16*128*2];   // 4 KB
    __shared__ __align__(16) char XIN[16*32*2];    // 1 KB
    __shared__ __align__(16) char XTt[16*32*2];    // 1 KB
    __shared__ __align__(16) char XT1[16*64*2];    // 2 KB

    const int tid = threadIdx.x, lane = tid & 63, w = tid >> 6;
    const int r0 = blockIdx.x * 16;
    const int c16 = lane & 15;
    const int rq = (lane >> 4) * 4;

    // ph0: load inputs (fp16, swizzled) + g part of cat
    for (int i = tid; i < 16*32; i += 256) {
        int r = i >> 5, c = i & 31;
        actst(XIN, 32, r, c, (_Float16)((c < 25) ? infect[(size_t)(r0+r)*25 + c] : 0.f));
        actst(XTt, 32, r, c, (_Float16)((c < 13) ? temp[(size_t)(r0+r)*13 + c] : 0.f));
    }
    for (int i = tid; i < 16*128; i += 256) {
        int r = i >> 7, u = i & 127;
        actst(CAT, 384, r, u, (_Float16)relu_(g_pre[(size_t)(r0+r)*128 + u] + bgfc[u]));
    }
    __syncthreads();

    // ph1: L1 (XIN -> S0, NT8 KC1) + T1 (XTt -> XT1, NT4 KC1)
    {
        h8 a = actld(XIN, 32, lane, 0);
        #pragma unroll
        for (int nt = w; nt < 8; nt += 4) {
            f32x4 acc = (f32x4){0.f,0.f,0.f,0.f};
            MFMA16(acc, a, frags[(size_t)(0 + nt)*64 + lane]);
            float bv = bi1[nt*16 + c16];
            #pragma unroll
            for (int q = 0; q < 4; ++q)
                actst(S0, 128, rq + q, nt*16 + c16, (_Float16)relu_(acc[q] + bv));
        }
        h8 at = actld(XTt, 32, lane, 0);
        {
            int nt = w;   // 4 tiles, one per wave
            f32x4 acc = (f32x4){0.f,0.f,0.f,0.f};
            MFMA16(acc, at, frags[(size_t)(72 + nt)*64 + lane]);
            float bv = bt1[nt*16 + c16];
            #pragma unroll
            for (int q = 0; q < 4; ++q)
                actst(XT1, 64, rq + q, nt*16 + c16, (_Float16)relu_(acc[q] + bv));
        }
    }
    __syncthreads();

    // ph2: L2 (S0 -> S1, NT8 KC4) + T2 (XT1 -> CAT[256..384), NT8 KC2)
    {
        h8 a[4];
        #pragma unroll
        for (int kc = 0; kc < 4; ++kc) a[kc] = actld(S0, 128, lane, kc);
        #pragma unroll
        for (int nt = w; nt < 8; nt += 4) {
            f32x4 acc = (f32x4){0.f,0.f,0.f,0.f};
            #pragma unroll
            for (int kc = 0; kc < 4; ++kc)
                MFMA16(acc, a[kc], frags[(size_t)(8 + nt*4 + kc)*64 + lane]);
            float bv = bi2[nt*16 + c16];
            #pragma unroll
            for (int q = 0; q < 4; ++q)
                actst(S1, 128, rq + q, nt*16 + c16, (_Float16)relu_(acc[q] + bv));
        }
        h8 a2[2];
        #pragma unroll
        for (int kc = 0; kc < 2; ++kc) a2[kc] = actld(XT1, 64, lane, kc);
        #pragma unroll
        for (int nt = w; nt < 8; nt += 4) {
            f32x4 acc = (f32x4){0.f,0.f,0.f,0.f};
            #pragma unroll
            for (int kc = 0; kc < 2; ++kc)
                MFMA16(acc, a2[kc], frags[(size_t)(76 + nt*2 + kc)*64 + lane]);
            float bv = bt2[nt*16 + c16];
            #pragma unroll
            for (int q = 0; q < 4; ++q)
                actst(CAT, 384, rq + q, 256 + nt*16 + c16, (_Float16)relu_(acc[q] + bv));
        }
    }
    __syncthreads();

    // ph3: L3 (S1 -> XT1 reused, NT4 KC4)
    {
        h8 a[4];
        #pragma unroll
        for (int kc = 0; kc < 4; ++kc) a[kc] = actld(S1, 128, lane, kc);
        int nt = w;   // 4 tiles
        f32x4 acc = (f32x4){0.f,0.f,0.f,0.f};
        #pragma unroll
        for (int kc = 0; kc < 4; ++kc)
            MFMA16(acc, a[kc], frags[(size_t)(40 + nt*4 + kc)*64 + lane]);
        float bv = bi3[nt*16 + c16];
        #pragma unroll
        for (int q = 0; q < 4; ++q)
            actst(XT1, 64, rq + q, nt*16 + c16, (_Float16)relu_(acc[q] + bv));
    }
    __syncthreads();

    // ph4: L4 (XT1 -> CAT[128..256), NT8 KC2)
    {
        h8 a[2];
        #pragma unroll
        for (int kc = 0; kc < 2; ++kc) a[kc] = actld(XT1, 64, lane, kc);
        #pragma unroll
        for (int nt = w; nt < 8; nt += 4) {
            f32x4 acc = (f32x4){0.f,0.f,0.f,0.f};
            #pragma unroll
            for (int kc = 0; kc < 2; ++kc)
                MFMA16(acc, a[kc], frags[(size_t)(56 + nt*2 + kc)*64 + lane]);
            float bv = bi4[nt*16 + c16];
            #pragma unroll
            for (int q = 0; q < 4; ++q)
                actst(CAT, 384, rq + q, 128 + nt*16 + c16, (_Float16)relu_(acc[q] + bv));
        }
    }
    __syncthreads();

    // ph5: li (CAT -> LIb, NT8 KC12)
    {
        h8 a[12];
        #pragma unroll
        for (int kc = 0; kc < 12; ++kc) a[kc] = actld(CAT, 384, lane, kc);
        #pragma unroll
        for (int nt = w; nt < 8; nt += 4) {
            f32x4 acc = (f32x4){0.f,0.f,0.f,0.f};
            #pragma unroll
            for (int kc = 0; kc < 12; ++kc)
                MFMA16(acc, a[kc], frags[(size_t)(92 + nt*12 + kc)*64 + lane]);
            float bv = bcat[nt*16 + c16];
            #pragma unroll
            for (int q = 0; q < 4; ++q)
                actst(LIb, 128, rq + q, nt*16 + c16, (_Float16)relu_(acc[q] + bv));
        }
    }
    __syncthreads();

    // ph6: xg = li @ Wih^T + bih + bhh (NT64 KC4), store global fp32
    {
        h8 a[4];
        #pragma unroll
        for (int kc = 0; kc < 4; ++kc) a[kc] = actld(LIb, 128, lane, kc);
        for (int nt = w; nt < 64; nt += 4) {
            f32x4 acc = (f32x4){0.f,0.f,0.f,0.f};
            #pragma unroll
            for (int kc = 0; kc < 4; ++kc)
                MFMA16(acc, a[kc], frags[(size_t)(188 + nt*4 + kc)*64 + lane]);
            int n = nt*16 + c16;
            float bv = bih[n] + bhh[n];
            #pragma unroll
            for (int q = 0; q < 4; ++q)
                xg[(size_t)(r0 + rq + q)*1024 + n] = acc[q] + bv;
        }
    }
}

// ---------------- pack Whh fp32 -> fp16 MFMA B-fragments (round-8) ----------
__global__ __launch_bounds__(256) void pack_whh_kernel(
    const float* __restrict__ Whh, h8* __restrict__ bregp,
    h8* __restrict__ bldsp)
{
    int i = blockIdx.x*256 + threadIdx.x;
    int w, j, kc, lane;
    bool isreg = (i < BREG_N);
    if (isreg) {
        w = i / (BREG_PW*64); int r = i % (BREG_PW*64);
        int fidx = r >> 6; lane = r & 63;
        j  = (fidx < 42) ? fidx / 6 : 7;
        kc = (fidx < 42) ? fidx % 6 : fidx - 42;
    } else {
        int L = i - BREG_N;
        if (L >= BLDS_N) return;
        w = L / (BLDS_PW*64); int r = L % (BLDS_PW*64);
        int fidx = r >> 6; lane = r & 63;
        j  = (fidx < 14) ? (fidx >> 1) : 7;
        kc = (fidx < 14) ? 6 + (fidx & 1) : 4 + (fidx - 14);
    }
    int row = 128*w + 16*j + (lane & 15);
    int col = 32*kc + 8*(lane >> 4);
    h8 v;
    #pragma unroll
    for (int e = 0; e < 8; ++e) v[e] = (_Float16)Whh[(long)row*HH + col + e];
    if (isreg) bregp[i] = v; else bldsp[i - BREG_N] = v;
}

// ---------------- LSTM (round-8 verified, 355 us) ----------------------------
__attribute__((amdgpu_waves_per_eu(2, 2)))
__global__ __launch_bounds__(512) void lstm_kernel(
    const float* __restrict__ xg, const h8* __restrict__ bregp,
    const h8* __restrict__ bldsp, const float* __restrict__ h0,
    const float* __restrict__ c0, float* __restrict__ hbuf)
{
    const int u = threadIdx.x;
    const int lane = u & 63;
    const int w = u >> 6;
    const int b = blockIdx.x;

    __shared__ __align__(16) h8 wlds[BLDS_N];        // 144 KB
    __shared__ float gbuf[1024];
    __shared__ __align__(16) _Float16 harr[2][HH];

    for (int i = u; i < BLDS_N; i += 512) wlds[i] = bldsp[i];

    h8 bfr[BREG_PW];
    {
        const h8* bp = bregp + (size_t)(w*BREG_PW)*64 + lane;
        #pragma unroll
        for (int m = 0; m < BREG_PW; ++m) bfr[m] = bp[(size_t)m*64];
    }

    float c = 0.f, h_last = 0.f;
    if (u < 256) { c = c0[b*HH + u]; harr[0][u] = (_Float16)h0[b*HH + u]; }
    __syncthreads();

    const float* xgb = xg + (size_t)b*TT*1024;
    const char* wbase = (const char*)wlds + w*(BLDS_PW*1024);
    const char* hbase = (const char*)harr;
    const int q16 = (lane >> 4) << 4;

    #pragma unroll 1
    for (int t = 0; t < TT; ++t) {
        const int cb = t & 1;
        float x0 = 0.f, x1 = 0.f, x2 = 0.f, x3 = 0.f;
        if (u < 256) {
            x0 = xgb[t*1024 + u];        x1 = xgb[t*1024 + 256 + u];
            x2 = xgb[t*1024 + 512 + u];  x3 = xgb[t*1024 + 768 + u];
        }
        h8 a[8];
        #pragma unroll
        for (int kc = 0; kc < 8; ++kc)
            a[kc] = *(const h8*)(hbase + cb*512 + kc*64 + q16);

        #pragma unroll
        for (int j = 0; j < 8; ++j) {
            f32x4 acc = (f32x4){0.f, 0.f, 0.f, 0.f};
            #pragma unroll
            for (int kc = 0; kc < 8; ++kc) {
                h8 bv;
                if ((j < 7) ? (kc < 6) : (kc < 4)) {
                    bv = bfr[(j < 7) ? (j*6 + kc) : (42 + kc)];
                } else {
                    unsigned off = (unsigned)(((j < 7) ? (j*2 + kc - 6)
                                                       : (14 + kc - 4))*1024 + lane*16);
                    asm volatile("" : "+v"(off));
                    bv = *(const h8*)(wbase + off);
                }
                acc = __builtin_amdgcn_mfma_f32_16x16x32_f16(a[kc], bv, acc, 0, 0, 0);
            }
            if (lane < 16) gbuf[w*128 + j*16 + lane] = acc[0];
        }
        __syncthreads();
        if (u < 256) {
            float gi = gbuf[u]       + x0;
            float gf = gbuf[256 + u] + x1;
            float gg = gbuf[512 + u] + x2;
            float go = gbuf[768 + u] + x3;
            c = sigmoid_(gf)*c + sigmoid_(gi)*tanhf(gg);
            float h = sigmoid_(go)*tanhf(c);
            harr[cb ^ 1][u] = (_Float16)h;
            h_last = h;
        }
        __syncthreads();
    }
    if (u < 256) hbuf[b*HH + u] = h_last;
}

// ---------------- final FC: out = relu(relu(h_T) @ Wfc + bfc) ---------------
__global__ __launch_bounds__(256) void final_fc_kernel(
    const float* __restrict__ hbuf, const float* __restrict__ Wfc,
    const float* __restrict__ bfc, float* __restrict__ out)
{
    int idx = blockIdx.x*256 + threadIdx.x;
    if (idx >= BB*N2) return;
    int b = idx / N2, j = idx - b*N2;
    const float* h = hbuf + b*HH;
    float o = bfc[j];
    for (int k = 0; k < HH; ++k) o += fmaxf(h[k], 0.f) * Wfc[(long)k*N2 + j];
    out[idx] = relu_(o);
}

extern "C" void kernel_launch(void* const* d_in, const int* in_sizes, int n_in,
                              void* d_out, int out_size, void* d_ws, size_t ws_size,
                              hipStream_t stream) {
    const float* nf     = (const float*)d_in[0];
    const int*   esrc   = (const int*)d_in[1];
    const int*   edst   = (const int*)d_in[2];
    const float* ew     = (const float*)d_in[3];
    const float* infect = (const float*)d_in[4];
    const float* temp   = (const float*)d_in[5];
    const float* h0     = (const float*)d_in[6];
    const float* c0     = (const float*)d_in[7];
    const float* Wg1    = (const float*)d_in[8];
    const float* bg1    = (const float*)d_in[9];
    const float* Wg2    = (const float*)d_in[10];
    const float* bg2    = (const float*)d_in[11];
    const float* Wgfc   = (const float*)d_in[12];
    const float* bgfc   = (const float*)d_in[13];
    const float* Wi1    = (const float*)d_in[14];
    const float* bi1    = (const float*)d_in[15];
    const float* Wi2    = (const float*)d_in[16];
    const float* bi2    = (const float*)d_in[17];
    const float* Wi3    = (const float*)d_in[18];
    const float* bi3    = (const float*)d_in[19];
    const float* Wi4    = (const float*)d_in[20];
    const float* bi4    = (const float*)d_in[21];
    const float* Wt1    = (const float*)d_in[22];
    const float* bt1    = (const float*)d_in[23];
    const float* Wt2    = (const float*)d_in[24];
    const float* bt2    = (const float*)d_in[25];
    const float* Wcat   = (const float*)d_in[26];
    const float* bcat   = (const float*)d_in[27];
    const float* Wih    = (const float*)d_in[28];
    const float* Whh    = (const float*)d_in[29];
    const float* bih    = (const float*)d_in[30];
    const float* bhh    = (const float*)d_in[31];
    const float* Wfc    = (const float*)d_in[32];
    const float* bfc    = (const float*)d_in[33];

    char* ws = (char*)d_ws;
    size_t off = 0;
    __hip_bfloat16* x2g = (__hip_bfloat16*)(ws + off); off += (size_t)BT*K2*2;
    __hip_bfloat16* WgfcT = (__hip_bfloat16*)(ws + off); off += (size_t)II*K2*2;
    float* g_pre = (float*)(ws + off); off += (size_t)BT*II*4;
    float* xg    = (float*)(ws + off); off += (size_t)BT*1024*4;
    float* hbuf  = (float*)(ws + off); off += (size_t)BB*HH*4;
    h8* bregp = (h8*)(ws + off); off += (size_t)BREG_N*16;
    h8* bldsp = (h8*)(ws + off); off += (size_t)BLDS_N*16;
    h8* frags = (h8*)(ws + off); off += (size_t)FR_TOTAL*64*16;

    hipMemsetAsync(g_pre, 0, (size_t)BT*II*4, stream);

    pack_whh_kernel<<<128, 256, 0, stream>>>(Whh, bregp, bldsp);
    pack_frags_kernel<<<FR_TOTAL, 64, 0, stream>>>(Wi1, Wi2, Wi3, Wi4, Wt1, Wt2,
                                                   Wcat, Wih, frags);
    packT_kernel<<<(K2 + 63)/64, 256, 0, stream>>>(Wgfc, WgfcT);
    gcn_kernel<<<BT, 256, 0, stream>>>(nf, esrc, edst, ew, Wg1, bg1, Wg2, bg2, x2g);
    gemm_kernel<<<dim3(BT/GBM, GCH), 256, 0, stream>>>(x2g, WgfcT, g_pre);
    blx_kernel<<<BT/16, 256, 0, stream>>>(infect, temp, g_pre, bgfc,
                                          bi1, bi2, bi3, bi4, bt1, bt2,
                                          bcat, bih, bhh, frags, xg);
    lstm_kernel<<<BB, 512, 0, stream>>>(xg, bregp, bldsp, h0, c0, hbuf);
    final_fc_kernel<<<(BB*N2 + 255)/256, 256, 0, stream>>>(hbuf, Wfc, bfc, (float*)d_out);
}

// Round 11
// 602.860 us; speedup vs baseline: 1.2981x; 1.1190x over previous
//
#include <hip/hip_runtime.h>
#include <hip/hip_bf16.h>

#define BB 8
#define TT 168
#define NN 425
#define EE 2048
#define II 128
#define HH 256
#define F1 10
#define F2 32
#define BT (BB*TT)       // 1344
#define K2 (NN*F2)       // 13600
#define N2 (2*NN)        // 850

// MFMA LSTM fragment bookkeeping (round-8 verified):
#define BREG_PW 46
#define BLDS_PW 18
#define BREG_N (8*BREG_PW*64)   // 23552 h8
#define BLDS_N (8*BLDS_PW*64)   // 9216 h8 = 144 KB

// blx fragment table: 444 frags total
#define FR_TOTAL 444

typedef _Float16 h2 __attribute__((ext_vector_type(2)));
typedef _Float16 h8 __attribute__((ext_vector_type(8)));
typedef short bf16x8 __attribute__((ext_vector_type(8)));
typedef float f32x4 __attribute__((ext_vector_type(4)));

__device__ __forceinline__ float relu_(float x){ return fmaxf(x, 0.f); }
__device__ __forceinline__ float sigmoid_(float x){ return 1.f/(1.f + expf(-x)); }

#define MFMA16(ACC, AV, BV) \
    ACC = __builtin_amdgcn_mfma_f32_16x16x32_f16((AV), (BV), (ACC), 0, 0, 0)

// packed fp16 LDS atomic add (ds_pk_add_f16, CDNA3+). Generic->LDS flat addr:
// low 32 bits of the flat address are the LDS byte offset on gfx9+.
__device__ __forceinline__ void ds_pk_add(h2* p, h2 v){
    unsigned a = (unsigned)(uintptr_t)p;
    asm volatile("ds_pk_add_f16 %0, %1" :: "v"(a), "v"(v) : "memory");
}

// swizzled fp16 activation LDS helpers (convention verified by passing gemm)
__device__ __forceinline__ h8 actld(const char* act, int K, int lane, int kc){
    int row = lane & 15;
    unsigned off = ((unsigned)(row*K + kc*32 + ((lane>>4)<<3))*2) ^ (unsigned)((row&7)<<4);
    return *(const h8*)(act + off);
}
__device__ __forceinline__ void actst(char* act, int K, int row, int col, _Float16 v){
    unsigned off = ((unsigned)(row*K + col)*2) ^ (unsigned)((row&7)<<4);
    *(_Float16*)(act + off) = v;
}

// ---------------- GCN: two layers fused, vectorized LDS + pk-fp16 atomics ---
__global__ __launch_bounds__(256) void gcn_kernel(
    const float* __restrict__ nf, const int* __restrict__ esrc,
    const int* __restrict__ edst, const float* __restrict__ ew,
    const float* __restrict__ Wg1, const float* __restrict__ bg1,
    const float* __restrict__ Wg2, const float* __restrict__ bg2,
    __hip_bfloat16* __restrict__ x2g)
{
    __shared__ float xs[NN];
    __shared__ float dinv[NN];
    __shared__ float agg1[NN];
    __shared__ float nrm[EE];
    __shared__ __align__(16) float x1p[NN*12];   // rows padded 10->12 (16B)
    __shared__ __align__(16) h2 agg2h[NN*8];     // rows padded 5->8 h2 (32B)
    __shared__ float wg1s[F1], bg1s[F1], wg2s[F1*F2], bg2s[F2];

    const int bt = blockIdx.x, tid = threadIdx.x;
    const long eb = (long)bt * EE;

    for (int v = tid; v < NN; v += 256) {
        xs[v] = nf[(long)bt*NN + v];
        dinv[v] = 1.0f;            // self-loop weight
        agg1[v] = 0.f;
    }
    for (int i = tid; i < NN*8; i += 256) agg2h[i] = (h2){(_Float16)0.f, (_Float16)0.f};
    if (tid < F1) { wg1s[tid] = Wg1[tid]; bg1s[tid] = bg1[tid]; }
    if (tid < F2) bg2s[tid] = bg2[tid];
    for (int i = tid; i < F1*F2; i += 256) wg2s[i] = Wg2[i];
    __syncthreads();

    for (int e = tid; e < EE; e += 256)
        atomicAdd(&dinv[edst[eb+e]], ew[eb+e]);
    __syncthreads();
    for (int v = tid; v < NN; v += 256) {
        float dg = dinv[v];
        dinv[v] = dg > 0.f ? 1.0f / sqrtf(fmaxf(dg, 1e-12f)) : 0.f;
    }
    __syncthreads();

    for (int e = tid; e < EE; e += 256) {
        int s = esrc[eb+e], d = edst[eb+e];
        float nm = dinv[s] * ew[eb+e] * dinv[d];
        nrm[e] = nm;
        atomicAdd(&agg1[d], nm * xs[s]);
    }
    __syncthreads();
    for (int v = tid; v < NN; v += 256) agg1[v] += dinv[v]*dinv[v]*xs[v];
    __syncthreads();
    for (int i = tid; i < NN*12; i += 256) {
        int v = i / 12, f = i - v*12;
        x1p[i] = (f < F1) ? relu_(agg1[v]*wg1s[f] + bg1s[f]) : 0.f;
    }
    __syncthreads();

    // layer-2 aggregation: vector x1 reads + 5 packed-fp16 atomics per edge
    for (int e = tid; e < EE; e += 256) {
        int s = esrc[eb+e], d = edst[eb+e];
        float nm = nrm[e];
        float4 a0 = *(const float4*)&x1p[s*12];
        float4 a1 = *(const float4*)&x1p[s*12+4];
        float2 a2 = *(const float2*)&x1p[s*12+8];
        h2 p0; p0[0] = (_Float16)(nm*a0.x); p0[1] = (_Float16)(nm*a0.y);
        h2 p1; p1[0] = (_Float16)(nm*a0.z); p1[1] = (_Float16)(nm*a0.w);
        h2 p2; p2[0] = (_Float16)(nm*a1.x); p2[1] = (_Float16)(nm*a1.y);
        h2 p3; p3[0] = (_Float16)(nm*a1.z); p3[1] = (_Float16)(nm*a1.w);
        h2 p4; p4[0] = (_Float16)(nm*a2.x); p4[1] = (_Float16)(nm*a2.y);
        ds_pk_add(&agg2h[d*8+0], p0);
        ds_pk_add(&agg2h[d*8+1], p1);
        ds_pk_add(&agg2h[d*8+2], p2);
        ds_pk_add(&agg2h[d*8+3], p3);
        ds_pk_add(&agg2h[d*8+4], p4);
    }
    __syncthreads();

    // x2 = (agg2_edges + dinv^2 * x1) @ Wg2 + bg2   (wg2 column in registers)
    {
        const int k = tid & 31;
        float wk[F1];
        #pragma unroll
        for (int f = 0; f < F1; ++f) wk[f] = wg2s[f*F2 + k];
        for (int i = tid; i < NN*F2; i += 256) {
            int v = i >> 5;
            float dv2 = dinv[v]*dinv[v];
            h8 r8 = *(const h8*)&agg2h[v*8];     // features 0..7
            h2 r2 = agg2h[v*8+4];                // features 8,9
            float4 a0 = *(const float4*)&x1p[v*12];
            float4 a1 = *(const float4*)&x1p[v*12+4];
            float2 a2 = *(const float2*)&x1p[v*12+8];
            float af[10];
            af[0]=(float)r8[0]+dv2*a0.x; af[1]=(float)r8[1]+dv2*a0.y;
            af[2]=(float)r8[2]+dv2*a0.z; af[3]=(float)r8[3]+dv2*a0.w;
            af[4]=(float)r8[4]+dv2*a1.x; af[5]=(float)r8[5]+dv2*a1.y;
            af[6]=(float)r8[6]+dv2*a1.z; af[7]=(float)r8[7]+dv2*a1.w;
            af[8]=(float)r2[0]+dv2*a2.x; af[9]=(float)r2[1]+dv2*a2.y;
            float o = bg2s[k];
            #pragma unroll
            for (int f = 0; f < F1; ++f) o += af[f]*wk[f];
            x2g[(long)bt*K2 + i] = __float2bfloat16(relu_(o));
        }
    }
}

// ---------------- transpose-pack Wgfc fp32 [13600,128] -> bf16 [128,13600] --
__global__ __launch_bounds__(256) void packT_kernel(
    const float* __restrict__ W, __hip_bfloat16* __restrict__ out)
{
    __shared__ float tile[64][129];
    const int k0 = blockIdx.x * 64, tid = threadIdx.x;
    for (int i = tid; i < 64*128; i += 256) {
        int r = i >> 7, j = i & 127;
        tile[r][j] = (k0 + r < K2) ? W[(size_t)(k0+r)*II + j] : 0.f;
    }
    __syncthreads();
    for (int i = tid; i < 64*128; i += 256) {
        int j = i >> 6, r = i & 63;
        if (k0 + r < K2) out[(size_t)j*K2 + k0 + r] = __float2bfloat16(tile[r][j]);
    }
}

// ---------------- MFMA bf16 GEMM, split-K: g_pre += x2 @ Wgfc ---------------
#define GBM 64
#define GBK 64
#define GCH 8
#define GST 27
__global__ __launch_bounds__(256) void gemm_kernel(
    const __hip_bfloat16* __restrict__ A, const __hip_bfloat16* __restrict__ Bt,
    float* __restrict__ C)
{
    __shared__ __align__(16) char As[2][GBM*GBK*2];
    __shared__ __align__(16) char Bs[2][II*GBK*2];
    const int tid = threadIdx.x;
    const int row0 = blockIdx.x * GBM;
    const int kbeg = blockIdx.y * (GST*GBK);
    const int wave = tid >> 6, lane = tid & 63;
    const int wm = wave >> 1, wn = wave & 1;
    const int l16 = lane & 15, lk = lane >> 4;
    const short* Aa = (const short*)A;
    const short* Bb = (const short*)Bt;

    const int ar = tid >> 2, ac = tid & 3;
    const int bc = tid >> 1, bh = (tid & 1) * 4;

    f32x4 acc[2][4];
    #pragma unroll
    for (int m = 0; m < 2; ++m)
        #pragma unroll
        for (int n = 0; n < 4; ++n) acc[m][n] = (f32x4){0.f,0.f,0.f,0.f};

    {
        #pragma unroll
        for (int j = 0; j < 2; ++j) {
            bf16x8 va = {0,0,0,0,0,0,0,0};
            int k = kbeg + ac*16 + j*8;
            if (k < K2) va = *(const bf16x8*)(Aa + (size_t)(row0+ar)*K2 + k);
            *(bf16x8*)(&As[0][0] + ((ar*128 + (ac*2+j)*16) ^ ((ar&7)<<4))) = va;
        }
        #pragma unroll
        for (int j = 0; j < 4; ++j) {
            bf16x8 vb = {0,0,0,0,0,0,0,0};
            int k = kbeg + (bh+j)*8;
            if (k < K2) vb = *(const bf16x8*)(Bb + (size_t)bc*K2 + k);
            *(bf16x8*)(&Bs[0][0] + ((bc*128 + (bh+j)*16) ^ ((bc&7)<<4))) = vb;
        }
    }
    __syncthreads();

    for (int s = 0; s < GST; ++s) {
        const int d = s & 1;
        bf16x8 pa[2], pb[4];
        #pragma unroll
        for (int j = 0; j < 2; ++j) pa[j] = (bf16x8){0,0,0,0,0,0,0,0};
        #pragma unroll
        for (int j = 0; j < 4; ++j) pb[j] = (bf16x8){0,0,0,0,0,0,0,0};
        if (s + 1 < GST) {
            int k0n = kbeg + (s+1)*GBK;
            #pragma unroll
            for (int j = 0; j < 2; ++j) {
                int k = k0n + ac*16 + j*8;
                if (k < K2) pa[j] = *(const bf16x8*)(Aa + (size_t)(row0+ar)*K2 + k);
            }
            #pragma unroll
            for (int j = 0; j < 4; ++j) {
                int k = k0n + (bh+j)*8;
                if (k < K2) pb[j] = *(const bf16x8*)(Bb + (size_t)bc*K2 + k);
            }
        }
        #pragma unroll
        for (int s2 = 0; s2 < 2; ++s2) {
            bf16x8 af[2], bf[4];
            #pragma unroll
            for (int m = 0; m < 2; ++m) {
                int row = wm*32 + m*16 + l16;
                af[m] = *(const bf16x8*)(&As[d][0] + ((row*128 + s2*64 + lk*16) ^ ((row&7)<<4)));
            }
            #pragma unroll
            for (int n = 0; n < 4; ++n) {
                int col = wn*64 + n*16 + l16;
                bf[n] = *(const bf16x8*)(&Bs[d][0] + ((col*128 + s2*64 + lk*16) ^ ((col&7)<<4)));
            }
            #pragma unroll
            for (int m = 0; m < 2; ++m)
                #pragma unroll
                for (int n = 0; n < 4; ++n)
                    acc[m][n] = __builtin_amdgcn_mfma_f32_16x16x32_bf16(af[m], bf[n], acc[m][n], 0, 0, 0);
        }
        if (s + 1 < GST) {
            #pragma unroll
            for (int j = 0; j < 2; ++j)
                *(bf16x8*)(&As[d^1][0] + ((ar*128 + (ac*2+j)*16) ^ ((ar&7)<<4))) = pa[j];
            #pragma unroll
            for (int j = 0; j < 4; ++j)
                *(bf16x8*)(&Bs[d^1][0] + ((bc*128 + (bh+j)*16) ^ ((bc&7)<<4))) = pb[j];
        }
        __syncthreads();
    }

    #pragma unroll
    for (int m = 0; m < 2; ++m)
        #pragma unroll
        for (int n = 0; n < 4; ++n)
            #pragma unroll
            for (int q = 0; q < 4; ++q)
                atomicAdd(&C[(size_t)(row0 + wm*32 + m*16 + lk*4 + q)*II + wn*64 + n*16 + l16],
                          acc[m][n][q]);
}

// ---------------- pack branch/cat/ih weights into MFMA B-fragments ----------
__global__ __launch_bounds__(64) void pack_frags_kernel(
    const float* __restrict__ Wi1, const float* __restrict__ Wi2,
    const float* __restrict__ Wi3, const float* __restrict__ Wi4,
    const float* __restrict__ Wt1, const float* __restrict__ Wt2,
    const float* __restrict__ Wcat, const float* __restrict__ Wih,
    h8* __restrict__ out)
{
    int f = blockIdx.x, l = threadIdx.x;
    const float* S; int sn, sk, K, KC, base;
    if      (f < 8)   { S=Wi1;  sn=1;   sk=128; K=25;  KC=1;  base=0;  }
    else if (f < 40)  { S=Wi2;  sn=1;   sk=128; K=128; KC=4;  base=8;  }
    else if (f < 56)  { S=Wi3;  sn=1;   sk=64;  K=128; KC=4;  base=40; }
    else if (f < 72)  { S=Wi4;  sn=1;   sk=128; K=64;  KC=2;  base=56; }
    else if (f < 76)  { S=Wt1;  sn=1;   sk=64;  K=13;  KC=1;  base=72; }
    else if (f < 92)  { S=Wt2;  sn=1;   sk=128; K=64;  KC=2;  base=76; }
    else if (f < 188) { S=Wcat; sn=1;   sk=128; K=384; KC=12; base=92; }
    else              { S=Wih;  sn=128; sk=1;   K=128; KC=4;  base=188;}
    int loc = f - base, nt = loc / KC, kc = loc % KC;
    int n = nt*16 + (l & 15);
    int k0 = kc*32 + ((l >> 4) << 3);
    h8 v;
    #pragma unroll
    for (int e = 0; e < 8; ++e) {
        int k = k0 + e;
        v[e] = (_Float16)((k < K) ? S[(size_t)n*sn + (size_t)k*sk] : 0.f);
    }
    out[(size_t)f*64 + l] = v;
}

// ------- fused branches + concat + li + xg, all MFMA (16 bt-rows/block) -----
__global__ __launch_bounds__(256) void blx_kernel(
    const float* __restrict__ infect, const float* __restrict__ temp,
    const float* __restrict__ g_pre, const float* __restrict__ bgfc,
    const float* __restrict__ bi1, const float* __restrict__ bi2,
    const float* __restrict__ bi3, const float* __restrict__ bi4,
    const float* __restrict__ bt1, const float* __restrict__ bt2,
    const float* __restrict__ bcat, const float* __restrict__ bih,
    const float* __restrict__ bhh, const h8* __restrict__ frags,
    float* __restrict__ xg)
{
    __shared__ __align__(16) char CAT[16*384*2];
    __shared__ __align__(16) char S0[16*128*2];
    __shared__ __align__(16) char S1[16*128*2];
    __shared__ __align__(16) char LIb[16*128*2];
    __shared__ __align__(16) char XIN[16*32*2];
    __shared__ __align__(16) char XTt[16*32*2];
    __shared__ __align__(16) char XT1[16*64*2];

    const int tid = threadIdx.x, lane = tid & 63, w = tid >> 6;
    const int r0 = blockIdx.x * 16;
    const int c16 = lane & 15;
    const int rq = (lane >> 4) * 4;

    for (int i = tid; i < 16*32; i += 256) {
        int r = i >> 5, c = i & 31;
        actst(XIN, 32, r, c, (_Float16)((c < 25) ? infect[(size_t)(r0+r)*25 + c] : 0.f));
        actst(XTt, 32, r, c, (_Float16)((c < 13) ? temp[(size_t)(r0+r)*13 + c] : 0.f));
    }
    for (int i = tid; i < 16*128; i += 256) {
        int r = i >> 7, u = i & 127;
        actst(CAT, 384, r, u, (_Float16)relu_(g_pre[(size_t)(r0+r)*128 + u] + bgfc[u]));
    }
    __syncthreads();

    {
        h8 a = actld(XIN, 32, lane, 0);
        #pragma unroll
        for (int nt = w; nt < 8; nt += 4) {
            f32x4 acc = (f32x4){0.f,0.f,0.f,0.f};
            MFMA16(acc, a, frags[(size_t)(0 + nt)*64 + lane]);
            float bv = bi1[nt*16 + c16];
            #pragma unroll
            for (int q = 0; q < 4; ++q)
                actst(S0, 128, rq + q, nt*16 + c16, (_Float16)relu_(acc[q] + bv));
        }
        h8 at = actld(XTt, 32, lane, 0);
        {
            int nt = w;
            f32x4 acc = (f32x4){0.f,0.f,0.f,0.f};
            MFMA16(acc, at, frags[(size_t)(72 + nt)*64 + lane]);
            float bv = bt1[nt*16 + c16];
            #pragma unroll
            for (int q = 0; q < 4; ++q)
                actst(XT1, 64, rq + q, nt*16 + c16, (_Float16)relu_(acc[q] + bv));
        }
    }
    __syncthreads();

    {
        h8 a[4];
        #pragma unroll
        for (int kc = 0; kc < 4; ++kc) a[kc] = actld(S0, 128, lane, kc);
        #pragma unroll
        for (int nt = w; nt < 8; nt += 4) {
            f32x4 acc = (f32x4){0.f,0.f,0.f,0.f};
            #pragma unroll
            for (int kc = 0; kc < 4; ++kc)
                MFMA16(acc, a[kc], frags[(size_t)(8 + nt*4 + kc)*64 + lane]);
            float bv = bi2[nt*16 + c16];
            #pragma unroll
            for (int q = 0; q < 4; ++q)
                actst(S1, 128, rq + q, nt*16 + c16, (_Float16)relu_(acc[q] + bv));
        }
        h8 a2[2];
        #pragma unroll
        for (int kc = 0; kc < 2; ++kc) a2[kc] = actld(XT1, 64, lane, kc);
        #pragma unroll
        for (int nt = w; nt < 8; nt += 4) {
            f32x4 acc = (f32x4){0.f,0.f,0.f,0.f};
            #pragma unroll
            for (int kc = 0; kc < 2; ++kc)
                MFMA16(acc, a2[kc], frags[(size_t)(76 + nt*2 + kc)*64 + lane]);
            float bv = bt2[nt*16 + c16];
            #pragma unroll
            for (int q = 0; q < 4; ++q)
                actst(CAT, 384, rq + q, 256 + nt*16 + c16, (_Float16)relu_(acc[q] + bv));
        }
    }
    __syncthreads();

    {
        h8 a[4];
        #pragma unroll
        for (int kc = 0; kc < 4; ++kc) a[kc] = actld(S1, 128, lane, kc);
        int nt = w;
        f32x4 acc = (f32x4){0.f,0.f,0.f,0.f};
        #pragma unroll
        for (int kc = 0; kc < 4; ++kc)
            MFMA16(acc, a[kc], frags[(size_t)(40 + nt*4 + kc)*64 + lane]);
        float bv = bi3[nt*16 + c16];
        #pragma unroll
        for (int q = 0; q < 4; ++q)
            actst(XT1, 64, rq + q, nt*16 + c16, (_Float16)relu_(acc[q] + bv));
    }
    __syncthreads();

    {
        h8 a[2];
        #pragma unroll
        for (int kc = 0; kc < 2; ++kc) a[kc] = actld(XT1, 64, lane, kc);
        #pragma unroll
        for (int nt = w; nt < 8; nt += 4) {
            f32x4 acc = (f32x4){0.f,0.f,0.f,0.f};
            #pragma unroll
            for (int kc = 0; kc < 2; ++kc)
                MFMA16(acc, a[kc], frags[(size_t)(56 + nt*2 + kc)*64 + lane]);
            float bv = bi4[nt*16 + c16];
            #pragma unroll
            for (int q = 0; q < 4; ++q)
                actst(CAT, 384, rq + q, 128 + nt*16 + c16, (_Float16)relu_(acc[q] + bv));
        }
    }
    __syncthreads();

    {
        h8 a[12];
        #pragma unroll
        for (int kc = 0; kc < 12; ++kc) a[kc] = actld(CAT, 384, lane, kc);
        #pragma unroll
        for (int nt = w; nt < 8; nt += 4) {
            f32x4 acc = (f32x4){0.f,0.f,0.f,0.f};
            #pragma unroll
            for (int kc = 0; kc < 12; ++kc)
                MFMA16(acc, a[kc], frags[(size_t)(92 + nt*12 + kc)*64 + lane]);
            float bv = bcat[nt*16 + c16];
            #pragma unroll
            for (int q = 0; q < 4; ++q)
                actst(LIb, 128, rq + q, nt*16 + c16, (_Float16)relu_(acc[q] + bv));
        }
    }
    __syncthreads();

    {
        h8 a[4];
        #pragma unroll
        for (int kc = 0; kc < 4; ++kc) a[kc] = actld(LIb, 128, lane, kc);
        for (int nt = w; nt < 64; nt += 4) {
            f32x4 acc = (f32x4){0.f,0.f,0.f,0.f};
            #pragma unroll
            for (int kc = 0; kc < 4; ++kc)
                MFMA16(acc, a[kc], frags[(size_t)(188 + nt*4 + kc)*64 + lane]);
            int n = nt*16 + c16;
            float bv = bih[n] + bhh[n];
            #pragma unroll
            for (int q = 0; q < 4; ++q)
                xg[(size_t)(r0 + rq + q)*1024 + n] = acc[q] + bv;
        }
    }
}

// ---------------- pack Whh fp32 -> fp16 MFMA B-fragments (round-8) ----------
__global__ __launch_bounds__(256) void pack_whh_kernel(
    const float* __restrict__ Whh, h8* __restrict__ bregp,
    h8* __restrict__ bldsp)
{
    int i = blockIdx.x*256 + threadIdx.x;
    int w, j, kc, lane;
    bool isreg = (i < BREG_N);
    if (isreg) {
        w = i / (BREG_PW*64); int r = i % (BREG_PW*64);
        int fidx = r >> 6; lane = r & 63;
        j  = (fidx < 42) ? fidx / 6 : 7;
        kc = (fidx < 42) ? fidx % 6 : fidx - 42;
    } else {
        int L = i - BREG_N;
        if (L >= BLDS_N) return;
        w = L / (BLDS_PW*64); int r = L % (BLDS_PW*64);
        int fidx = r >> 6; lane = r & 63;
        j  = (fidx < 14) ? (fidx >> 1) : 7;
        kc = (fidx < 14) ? 6 + (fidx & 1) : 4 + (fidx - 14);
    }
    int row = 128*w + 16*j + (lane & 15);
    int col = 32*kc + 8*(lane >> 4);
    h8 v;
    #pragma unroll
    for (int e = 0; e < 8; ++e) v[e] = (_Float16)Whh[(long)row*HH + col + e];
    if (isreg) bregp[i] = v; else bldsp[i - BREG_N] = v;
}

// ---------------- LSTM (round-8 verified, 355 us) ----------------------------
__attribute__((amdgpu_waves_per_eu(2, 2)))
__global__ __launch_bounds__(512) void lstm_kernel(
    const float* __restrict__ xg, const h8* __restrict__ bregp,
    const h8* __restrict__ bldsp, const float* __restrict__ h0,
    const float* __restrict__ c0, float* __restrict__ hbuf)
{
    const int u = threadIdx.x;
    const int lane = u & 63;
    const int w = u >> 6;
    const int b = blockIdx.x;

    __shared__ __align__(16) h8 wlds[BLDS_N];
    __shared__ float gbuf[1024];
    __shared__ __align__(16) _Float16 harr[2][HH];

    for (int i = u; i < BLDS_N; i += 512) wlds[i] = bldsp[i];

    h8 bfr[BREG_PW];
    {
        const h8* bp = bregp + (size_t)(w*BREG_PW)*64 + lane;
        #pragma unroll
        for (int m = 0; m < BREG_PW; ++m) bfr[m] = bp[(size_t)m*64];
    }

    float c = 0.f, h_last = 0.f;
    if (u < 256) { c = c0[b*HH + u]; harr[0][u] = (_Float16)h0[b*HH + u]; }
    __syncthreads();

    const float* xgb = xg + (size_t)b*TT*1024;
    const char* wbase = (const char*)wlds + w*(BLDS_PW*1024);
    const char* hbase = (const char*)harr;
    const int q16 = (lane >> 4) << 4;

    #pragma unroll 1
    for (int t = 0; t < TT; ++t) {
        const int cb = t & 1;
        float x0 = 0.f, x1 = 0.f, x2 = 0.f, x3 = 0.f;
        if (u < 256) {
            x0 = xgb[t*1024 + u];        x1 = xgb[t*1024 + 256 + u];
            x2 = xgb[t*1024 + 512 + u];  x3 = xgb[t*1024 + 768 + u];
        }
        h8 a[8];
        #pragma unroll
        for (int kc = 0; kc < 8; ++kc)
            a[kc] = *(const h8*)(hbase + cb*512 + kc*64 + q16);

        #pragma unroll
        for (int j = 0; j < 8; ++j) {
            f32x4 acc = (f32x4){0.f, 0.f, 0.f, 0.f};
            #pragma unroll
            for (int kc = 0; kc < 8; ++kc) {
                h8 bv;
                if ((j < 7) ? (kc < 6) : (kc < 4)) {
                    bv = bfr[(j < 7) ? (j*6 + kc) : (42 + kc)];
                } else {
                    unsigned off = (unsigned)(((j < 7) ? (j*2 + kc - 6)
                                                       : (14 + kc - 4))*1024 + lane*16);
                    asm volatile("" : "+v"(off));
                    bv = *(const h8*)(wbase + off);
                }
                acc = __builtin_amdgcn_mfma_f32_16x16x32_f16(a[kc], bv, acc, 0, 0, 0);
            }
            if (lane < 16) gbuf[w*128 + j*16 + lane] = acc[0];
        }
        __syncthreads();
        if (u < 256) {
            float gi = gbuf[u]       + x0;
            float gf = gbuf[256 + u] + x1;
            float gg = gbuf[512 + u] + x2;
            float go = gbuf[768 + u] + x3;
            c = sigmoid_(gf)*c + sigmoid_(gi)*tanhf(gg);
            float h = sigmoid_(go)*tanhf(c);
            harr[cb ^ 1][u] = (_Float16)h;
            h_last = h;
        }
        __syncthreads();
    }
    if (u < 256) hbuf[b*HH + u] = h_last;
}

// ---------------- final FC: out = relu(relu(h_T) @ Wfc + bfc) ---------------
__global__ __launch_bounds__(256) void final_fc_kernel(
    const float* __restrict__ hbuf, const float* __restrict__ Wfc,
    const float* __restrict__ bfc, float* __restrict__ out)
{
    int idx = blockIdx.x*256 + threadIdx.x;
    if (idx >= BB*N2) return;
    int b = idx / N2, j = idx - b*N2;
    const float* h = hbuf + b*HH;
    float o = bfc[j];
    for (int k = 0; k < HH; ++k) o += fmaxf(h[k], 0.f) * Wfc[(long)k*N2 + j];
    out[idx] = relu_(o);
}

extern "C" void kernel_launch(void* const* d_in, const int* in_sizes, int n_in,
                              void* d_out, int out_size, void* d_ws, size_t ws_size,
                              hipStream_t stream) {
    const float* nf     = (const float*)d_in[0];
    const int*   esrc   = (const int*)d_in[1];
    const int*   edst   = (const int*)d_in[2];
    const float* ew     = (const float*)d_in[3];
    const float* infect = (const float*)d_in[4];
    const float* temp   = (const float*)d_in[5];
    const float* h0     = (const float*)d_in[6];
    const float* c0     = (const float*)d_in[7];
    const float* Wg1    = (const float*)d_in[8];
    const float* bg1    = (const float*)d_in[9];
    const float* Wg2    = (const float*)d_in[10];
    const float* bg2    = (const float*)d_in[11];
    const float* Wgfc   = (const float*)d_in[12];
    const float* bgfc   = (const float*)d_in[13];
    const float* Wi1    = (const float*)d_in[14];
    const float* bi1    = (const float*)d_in[15];
    const float* Wi2    = (const float*)d_in[16];
    const float* bi2    = (const float*)d_in[17];
    const float* Wi3    = (const float*)d_in[18];
    const float* bi3    = (const float*)d_in[19];
    const float* Wi4    = (const float*)d_in[20];
    const float* bi4    = (const float*)d_in[21];
    const float* Wt1    = (const float*)d_in[22];
    const float* bt1    = (const float*)d_in[23];
    const float* Wt2    = (const float*)d_in[24];
    const float* bt2    = (const float*)d_in[25];
    const float* Wcat   = (const float*)d_in[26];
    const float* bcat   = (const float*)d_in[27];
    const float* Wih    = (const float*)d_in[28];
    const float* Whh    = (const float*)d_in[29];
    const float* bih    = (const float*)d_in[30];
    const float* bhh    = (const float*)d_in[31];
    const float* Wfc    = (const float*)d_in[32];
    const float* bfc    = (const float*)d_in[33];

    char* ws = (char*)d_ws;
    size_t off = 0;
    __hip_bfloat16* x2g = (__hip_bfloat16*)(ws + off); off += (size_t)BT*K2*2;
    __hip_bfloat16* WgfcT = (__hip_bfloat16*)(ws + off); off += (size_t)II*K2*2;
    float* g_pre = (float*)(ws + off); off += (size_t)BT*II*4;
    float* xg    = (float*)(ws + off); off += (size_t)BT*1024*4;
    float* hbuf  = (float*)(ws + off); off += (size_t)BB*HH*4;
    h8* bregp = (h8*)(ws + off); off += (size_t)BREG_N*16;
    h8* bldsp = (h8*)(ws + off); off += (size_t)BLDS_N*16;
    h8* frags = (h8*)(ws + off); off += (size_t)FR_TOTAL*64*16;

    hipMemsetAsync(g_pre, 0, (size_t)BT*II*4, stream);

    pack_whh_kernel<<<128, 256, 0, stream>>>(Whh, bregp, bldsp);
    pack_frags_kernel<<<FR_TOTAL, 64, 0, stream>>>(Wi1, Wi2, Wi3, Wi4, Wt1, Wt2,
                                                   Wcat, Wih, frags);
    packT_kernel<<<(K2 + 63)/64, 256, 0, stream>>>(Wgfc, WgfcT);
    gcn_kernel<<<BT, 256, 0, stream>>>(nf, esrc, edst, ew, Wg1, bg1, Wg2, bg2, x2g);
    gemm_kernel<<<dim3(BT/GBM, GCH), 256, 0, stream>>>(x2g, WgfcT, g_pre);
    blx_kernel<<<BT/16, 256, 0, stream>>>(infect, temp, g_pre, bgfc,
                                          bi1, bi2, bi3, bi4, bt1, bt2,
                                          bcat, bih, bhh, frags, xg);
    lstm_kernel<<<BB, 512, 0, stream>>>(xg, bregp, bldsp, h0, c0, hbuf);
    final_fc_kernel<<<(BB*N2 + 255)/256, 256, 0, stream>>>(hbuf, Wfc, bfc, (float*)d_out);
}

// Round 12
// 572.392 us; speedup vs baseline: 1.3672x; 1.0532x over previous
//
#include <hip/hip_runtime.h>
#include <hip/hip_bf16.h>

#define BB 8
#define TT 168
#define NN 425
#define EE 2048
#define II 128
#define HH 256
#define F1 10
#define F2 32
#define BT (BB*TT)       // 1344
#define K2 (NN*F2)       // 13600
#define N2 (2*NN)        // 850

// MFMA LSTM fragment bookkeeping (round-8 verified mapping):
#define BREG_PW 46
#define BLDS_PW 18
#define BREG_N (8*BREG_PW*64)   // 23552 h8
#define BLDS_N (8*BLDS_PW*64)   // 9216 h8 = 144 KB
#define LB 2                    // batches per LSTM block (M-packed)

// blx fragment table: 444 frags total
#define FR_TOTAL 444

typedef _Float16 h2 __attribute__((ext_vector_type(2)));
typedef _Float16 h8 __attribute__((ext_vector_type(8)));
typedef short bf16x8 __attribute__((ext_vector_type(8)));
typedef float f32x4 __attribute__((ext_vector_type(4)));

__device__ __forceinline__ float relu_(float x){ return fmaxf(x, 0.f); }
__device__ __forceinline__ float sigmoid_(float x){ return 1.f/(1.f + expf(-x)); }

#define MFMA16(ACC, AV, BV) \
    ACC = __builtin_amdgcn_mfma_f32_16x16x32_f16((AV), (BV), (ACC), 0, 0, 0)

// packed fp16 LDS atomic add (ds_pk_add_f16, CDNA3+)
__device__ __forceinline__ void ds_pk_add(h2* p, h2 v){
    unsigned a = (unsigned)(uintptr_t)p;
    asm volatile("ds_pk_add_f16 %0, %1" :: "v"(a), "v"(v) : "memory");
}

// swizzled fp16 activation LDS helpers (convention verified by passing gemm)
__device__ __forceinline__ h8 actld(const char* act, int K, int lane, int kc){
    int row = lane & 15;
    unsigned off = ((unsigned)(row*K + kc*32 + ((lane>>4)<<3))*2) ^ (unsigned)((row&7)<<4);
    return *(const h8*)(act + off);
}
__device__ __forceinline__ void actst(char* act, int K, int row, int col, _Float16 v){
    unsigned off = ((unsigned)(row*K + col)*2) ^ (unsigned)((row&7)<<4);
    *(_Float16*)(act + off) = v;
}

// ---------------- GCN: two layers fused, vectorized LDS + pk-fp16 atomics ---
__global__ __launch_bounds__(256) void gcn_kernel(
    const float* __restrict__ nf, const int* __restrict__ esrc,
    const int* __restrict__ edst, const float* __restrict__ ew,
    const float* __restrict__ Wg1, const float* __restrict__ bg1,
    const float* __restrict__ Wg2, const float* __restrict__ bg2,
    __hip_bfloat16* __restrict__ x2g)
{
    __shared__ float xs[NN];
    __shared__ float dinv[NN];
    __shared__ float agg1[NN];
    __shared__ float nrm[EE];
    __shared__ __align__(16) float x1p[NN*12];
    __shared__ __align__(16) h2 agg2h[NN*8];
    __shared__ float wg1s[F1], bg1s[F1], wg2s[F1*F2], bg2s[F2];

    const int bt = blockIdx.x, tid = threadIdx.x;
    const long eb = (long)bt * EE;

    for (int v = tid; v < NN; v += 256) {
        xs[v] = nf[(long)bt*NN + v];
        dinv[v] = 1.0f;
        agg1[v] = 0.f;
    }
    for (int i = tid; i < NN*8; i += 256) agg2h[i] = (h2){(_Float16)0.f, (_Float16)0.f};
    if (tid < F1) { wg1s[tid] = Wg1[tid]; bg1s[tid] = bg1[tid]; }
    if (tid < F2) bg2s[tid] = bg2[tid];
    for (int i = tid; i < F1*F2; i += 256) wg2s[i] = Wg2[i];
    __syncthreads();

    for (int e = tid; e < EE; e += 256)
        atomicAdd(&dinv[edst[eb+e]], ew[eb+e]);
    __syncthreads();
    for (int v = tid; v < NN; v += 256) {
        float dg = dinv[v];
        dinv[v] = dg > 0.f ? 1.0f / sqrtf(fmaxf(dg, 1e-12f)) : 0.f;
    }
    __syncthreads();

    for (int e = tid; e < EE; e += 256) {
        int s = esrc[eb+e], d = edst[eb+e];
        float nm = dinv[s] * ew[eb+e] * dinv[d];
        nrm[e] = nm;
        atomicAdd(&agg1[d], nm * xs[s]);
    }
    __syncthreads();
    for (int v = tid; v < NN; v += 256) agg1[v] += dinv[v]*dinv[v]*xs[v];
    __syncthreads();
    for (int i = tid; i < NN*12; i += 256) {
        int v = i / 12, f = i - v*12;
        x1p[i] = (f < F1) ? relu_(agg1[v]*wg1s[f] + bg1s[f]) : 0.f;
    }
    __syncthreads();

    for (int e = tid; e < EE; e += 256) {
        int s = esrc[eb+e], d = edst[eb+e];
        float nm = nrm[e];
        float4 a0 = *(const float4*)&x1p[s*12];
        float4 a1 = *(const float4*)&x1p[s*12+4];
        float2 a2 = *(const float2*)&x1p[s*12+8];
        h2 p0; p0[0] = (_Float16)(nm*a0.x); p0[1] = (_Float16)(nm*a0.y);
        h2 p1; p1[0] = (_Float16)(nm*a0.z); p1[1] = (_Float16)(nm*a0.w);
        h2 p2; p2[0] = (_Float16)(nm*a1.x); p2[1] = (_Float16)(nm*a1.y);
        h2 p3; p3[0] = (_Float16)(nm*a1.z); p3[1] = (_Float16)(nm*a1.w);
        h2 p4; p4[0] = (_Float16)(nm*a2.x); p4[1] = (_Float16)(nm*a2.y);
        ds_pk_add(&agg2h[d*8+0], p0);
        ds_pk_add(&agg2h[d*8+1], p1);
        ds_pk_add(&agg2h[d*8+2], p2);
        ds_pk_add(&agg2h[d*8+3], p3);
        ds_pk_add(&agg2h[d*8+4], p4);
    }
    __syncthreads();

    {
        const int k = tid & 31;
        float wk[F1];
        #pragma unroll
        for (int f = 0; f < F1; ++f) wk[f] = wg2s[f*F2 + k];
        for (int i = tid; i < NN*F2; i += 256) {
            int v = i >> 5;
            float dv2 = dinv[v]*dinv[v];
            h8 r8 = *(const h8*)&agg2h[v*8];
            h2 r2 = agg2h[v*8+4];
            float4 a0 = *(const float4*)&x1p[v*12];
            float4 a1 = *(const float4*)&x1p[v*12+4];
            float2 a2 = *(const float2*)&x1p[v*12+8];
            float af[10];
            af[0]=(float)r8[0]+dv2*a0.x; af[1]=(float)r8[1]+dv2*a0.y;
            af[2]=(float)r8[2]+dv2*a0.z; af[3]=(float)r8[3]+dv2*a0.w;
            af[4]=(float)r8[4]+dv2*a1.x; af[5]=(float)r8[5]+dv2*a1.y;
            af[6]=(float)r8[6]+dv2*a1.z; af[7]=(float)r8[7]+dv2*a1.w;
            af[8]=(float)r2[0]+dv2*a2.x; af[9]=(float)r2[1]+dv2*a2.y;
            float o = bg2s[k];
            #pragma unroll
            for (int f = 0; f < F1; ++f) o += af[f]*wk[f];
            x2g[(long)bt*K2 + i] = __float2bfloat16(relu_(o));
        }
    }
}

// ---------------- transpose-pack Wgfc fp32 [13600,128] -> bf16 [128,13600] --
__global__ __launch_bounds__(256) void packT_kernel(
    const float* __restrict__ W, __hip_bfloat16* __restrict__ out)
{
    __shared__ float tile[64][129];
    const int k0 = blockIdx.x * 64, tid = threadIdx.x;
    for (int i = tid; i < 64*128; i += 256) {
        int r = i >> 7, j = i & 127;
        tile[r][j] = (k0 + r < K2) ? W[(size_t)(k0+r)*II + j] : 0.f;
    }
    __syncthreads();
    for (int i = tid; i < 64*128; i += 256) {
        int j = i >> 6, r = i & 63;
        if (k0 + r < K2) out[(size_t)j*K2 + k0 + r] = __float2bfloat16(tile[r][j]);
    }
}

// ---------------- MFMA bf16 GEMM, split-K: g_pre += x2 @ Wgfc ---------------
#define GBM 64
#define GBK 64
#define GCH 8
#define GST 27
__global__ __launch_bounds__(256) void gemm_kernel(
    const __hip_bfloat16* __restrict__ A, const __hip_bfloat16* __restrict__ Bt,
    float* __restrict__ C)
{
    __shared__ __align__(16) char As[2][GBM*GBK*2];
    __shared__ __align__(16) char Bs[2][II*GBK*2];
    const int tid = threadIdx.x;
    const int row0 = blockIdx.x * GBM;
    const int kbeg = blockIdx.y * (GST*GBK);
    const int wave = tid >> 6, lane = tid & 63;
    const int wm = wave >> 1, wn = wave & 1;
    const int l16 = lane & 15, lk = lane >> 4;
    const short* Aa = (const short*)A;
    const short* Bb = (const short*)Bt;

    const int ar = tid >> 2, ac = tid & 3;
    const int bc = tid >> 1, bh = (tid & 1) * 4;

    f32x4 acc[2][4];
    #pragma unroll
    for (int m = 0; m < 2; ++m)
        #pragma unroll
        for (int n = 0; n < 4; ++n) acc[m][n] = (f32x4){0.f,0.f,0.f,0.f};

    {
        #pragma unroll
        for (int j = 0; j < 2; ++j) {
            bf16x8 va = {0,0,0,0,0,0,0,0};
            int k = kbeg + ac*16 + j*8;
            if (k < K2) va = *(const bf16x8*)(Aa + (size_t)(row0+ar)*K2 + k);
            *(bf16x8*)(&As[0][0] + ((ar*128 + (ac*2+j)*16) ^ ((ar&7)<<4))) = va;
        }
        #pragma unroll
        for (int j = 0; j < 4; ++j) {
            bf16x8 vb = {0,0,0,0,0,0,0,0};
            int k = kbeg + (bh+j)*8;
            if (k < K2) vb = *(const bf16x8*)(Bb + (size_t)bc*K2 + k);
            *(bf16x8*)(&Bs[0][0] + ((bc*128 + (bh+j)*16) ^ ((bc&7)<<4))) = vb;
        }
    }
    __syncthreads();

    for (int s = 0; s < GST; ++s) {
        const int d = s & 1;
        bf16x8 pa[2], pb[4];
        #pragma unroll
        for (int j = 0; j < 2; ++j) pa[j] = (bf16x8){0,0,0,0,0,0,0,0};
        #pragma unroll
        for (int j = 0; j < 4; ++j) pb[j] = (bf16x8){0,0,0,0,0,0,0,0};
        if (s + 1 < GST) {
            int k0n = kbeg + (s+1)*GBK;
            #pragma unroll
            for (int j = 0; j < 2; ++j) {
                int k = k0n + ac*16 + j*8;
                if (k < K2) pa[j] = *(const bf16x8*)(Aa + (size_t)(row0+ar)*K2 + k);
            }
            #pragma unroll
            for (int j = 0; j < 4; ++j) {
                int k = k0n + (bh+j)*8;
                if (k < K2) pb[j] = *(const bf16x8*)(Bb + (size_t)bc*K2 + k);
            }
        }
        #pragma unroll
        for (int s2 = 0; s2 < 2; ++s2) {
            bf16x8 af[2], bf[4];
            #pragma unroll
            for (int m = 0; m < 2; ++m) {
                int row = wm*32 + m*16 + l16;
                af[m] = *(const bf16x8*)(&As[d][0] + ((row*128 + s2*64 + lk*16) ^ ((row&7)<<4)));
            }
            #pragma unroll
            for (int n = 0; n < 4; ++n) {
                int col = wn*64 + n*16 + l16;
                bf[n] = *(const bf16x8*)(&Bs[d][0] + ((col*128 + s2*64 + lk*16) ^ ((col&7)<<4)));
            }
            #pragma unroll
            for (int m = 0; m < 2; ++m)
                #pragma unroll
                for (int n = 0; n < 4; ++n)
                    acc[m][n] = __builtin_amdgcn_mfma_f32_16x16x32_bf16(af[m], bf[n], acc[m][n], 0, 0, 0);
        }
        if (s + 1 < GST) {
            #pragma unroll
            for (int j = 0; j < 2; ++j)
                *(bf16x8*)(&As[d^1][0] + ((ar*128 + (ac*2+j)*16) ^ ((ar&7)<<4))) = pa[j];
            #pragma unroll
            for (int j = 0; j < 4; ++j)
                *(bf16x8*)(&Bs[d^1][0] + ((bc*128 + (bh+j)*16) ^ ((bc&7)<<4))) = pb[j];
        }
        __syncthreads();
    }

    #pragma unroll
    for (int m = 0; m < 2; ++m)
        #pragma unroll
        for (int n = 0; n < 4; ++n)
            #pragma unroll
            for (int q = 0; q < 4; ++q)
                atomicAdd(&C[(size_t)(row0 + wm*32 + m*16 + lk*4 + q)*II + wn*64 + n*16 + l16],
                          acc[m][n][q]);
}

// ---------------- pack branch/cat/ih weights into MFMA B-fragments ----------
__global__ __launch_bounds__(64) void pack_frags_kernel(
    const float* __restrict__ Wi1, const float* __restrict__ Wi2,
    const float* __restrict__ Wi3, const float* __restrict__ Wi4,
    const float* __restrict__ Wt1, const float* __restrict__ Wt2,
    const float* __restrict__ Wcat, const float* __restrict__ Wih,
    h8* __restrict__ out)
{
    int f = blockIdx.x, l = threadIdx.x;
    const float* S; int sn, sk, K, KC, base;
    if      (f < 8)   { S=Wi1;  sn=1;   sk=128; K=25;  KC=1;  base=0;  }
    else if (f < 40)  { S=Wi2;  sn=1;   sk=128; K=128; KC=4;  base=8;  }
    else if (f < 56)  { S=Wi3;  sn=1;   sk=64;  K=128; KC=4;  base=40; }
    else if (f < 72)  { S=Wi4;  sn=1;   sk=128; K=64;  KC=2;  base=56; }
    else if (f < 76)  { S=Wt1;  sn=1;   sk=64;  K=13;  KC=1;  base=72; }
    else if (f < 92)  { S=Wt2;  sn=1;   sk=128; K=64;  KC=2;  base=76; }
    else if (f < 188) { S=Wcat; sn=1;   sk=128; K=384; KC=12; base=92; }
    else              { S=Wih;  sn=128; sk=1;   K=128; KC=4;  base=188;}
    int loc = f - base, nt = loc / KC, kc = loc % KC;
    int n = nt*16 + (l & 15);
    int k0 = kc*32 + ((l >> 4) << 3);
    h8 v;
    #pragma unroll
    for (int e = 0; e < 8; ++e) {
        int k = k0 + e;
        v[e] = (_Float16)((k < K) ? S[(size_t)n*sn + (size_t)k*sk] : 0.f);
    }
    out[(size_t)f*64 + l] = v;
}

// ------- fused branches + concat + li + xg, all MFMA (16 bt-rows/block) -----
// xg4 layout: [bt][unit(256)][gate(4)] floats, gate order i,f,g,o
__global__ __launch_bounds__(256) void blx_kernel(
    const float* __restrict__ infect, const float* __restrict__ temp,
    const float* __restrict__ g_pre, const float* __restrict__ bgfc,
    const float* __restrict__ bi1, const float* __restrict__ bi2,
    const float* __restrict__ bi3, const float* __restrict__ bi4,
    const float* __restrict__ bt1, const float* __restrict__ bt2,
    const float* __restrict__ bcat, const float* __restrict__ bih,
    const float* __restrict__ bhh, const h8* __restrict__ frags,
    float* __restrict__ xg4)
{
    __shared__ __align__(16) char CAT[16*384*2];
    __shared__ __align__(16) char S0[16*128*2];
    __shared__ __align__(16) char S1[16*128*2];
    __shared__ __align__(16) char LIb[16*128*2];
    __shared__ __align__(16) char XIN[16*32*2];
    __shared__ __align__(16) char XTt[16*32*2];
    __shared__ __align__(16) char XT1[16*64*2];

    const int tid = threadIdx.x, lane = tid & 63, w = tid >> 6;
    const int r0 = blockIdx.x * 16;
    const int c16 = lane & 15;
    const int rq = (lane >> 4) * 4;

    for (int i = tid; i < 16*32; i += 256) {
        int r = i >> 5, c = i & 31;
        actst(XIN, 32, r, c, (_Float16)((c < 25) ? infect[(size_t)(r0+r)*25 + c] : 0.f));
        actst(XTt, 32, r, c, (_Float16)((c < 13) ? temp[(size_t)(r0+r)*13 + c] : 0.f));
    }
    for (int i = tid; i < 16*128; i += 256) {
        int r = i >> 7, u = i & 127;
        actst(CAT, 384, r, u, (_Float16)relu_(g_pre[(size_t)(r0+r)*128 + u] + bgfc[u]));
    }
    __syncthreads();

    {
        h8 a = actld(XIN, 32, lane, 0);
        #pragma unroll
        for (int nt = w; nt < 8; nt += 4) {
            f32x4 acc = (f32x4){0.f,0.f,0.f,0.f};
            MFMA16(acc, a, frags[(size_t)(0 + nt)*64 + lane]);
            float bv = bi1[nt*16 + c16];
            #pragma unroll
            for (int q = 0; q < 4; ++q)
                actst(S0, 128, rq + q, nt*16 + c16, (_Float16)relu_(acc[q] + bv));
        }
        h8 at = actld(XTt, 32, lane, 0);
        {
            int nt = w;
            f32x4 acc = (f32x4){0.f,0.f,0.f,0.f};
            MFMA16(acc, at, frags[(size_t)(72 + nt)*64 + lane]);
            float bv = bt1[nt*16 + c16];
            #pragma unroll
            for (int q = 0; q < 4; ++q)
                actst(XT1, 64, rq + q, nt*16 + c16, (_Float16)relu_(acc[q] + bv));
        }
    }
    __syncthreads();

    {
        h8 a[4];
        #pragma unroll
        for (int kc = 0; kc < 4; ++kc) a[kc] = actld(S0, 128, lane, kc);
        #pragma unroll
        for (int nt = w; nt < 8; nt += 4) {
            f32x4 acc = (f32x4){0.f,0.f,0.f,0.f};
            #pragma unroll
            for (int kc = 0; kc < 4; ++kc)
                MFMA16(acc, a[kc], frags[(size_t)(8 + nt*4 + kc)*64 + lane]);
            float bv = bi2[nt*16 + c16];
            #pragma unroll
            for (int q = 0; q < 4; ++q)
                actst(S1, 128, rq + q, nt*16 + c16, (_Float16)relu_(acc[q] + bv));
        }
        h8 a2[2];
        #pragma unroll
        for (int kc = 0; kc < 2; ++kc) a2[kc] = actld(XT1, 64, lane, kc);
        #pragma unroll
        for (int nt = w; nt < 8; nt += 4) {
            f32x4 acc = (f32x4){0.f,0.f,0.f,0.f};
            #pragma unroll
            for (int kc = 0; kc < 2; ++kc)
                MFMA16(acc, a2[kc], frags[(size_t)(76 + nt*2 + kc)*64 + lane]);
            float bv = bt2[nt*16 + c16];
            #pragma unroll
            for (int q = 0; q < 4; ++q)
                actst(CAT, 384, rq + q, 256 + nt*16 + c16, (_Float16)relu_(acc[q] + bv));
        }
    }
    __syncthreads();

    {
        h8 a[4];
        #pragma unroll
        for (int kc = 0; kc < 4; ++kc) a[kc] = actld(S1, 128, lane, kc);
        int nt = w;
        f32x4 acc = (f32x4){0.f,0.f,0.f,0.f};
        #pragma unroll
        for (int kc = 0; kc < 4; ++kc)
            MFMA16(acc, a[kc], frags[(size_t)(40 + nt*4 + kc)*64 + lane]);
        float bv = bi3[nt*16 + c16];
        #pragma unroll
        for (int q = 0; q < 4; ++q)
            actst(XT1, 64, rq + q, nt*16 + c16, (_Float16)relu_(acc[q] + bv));
    }
    __syncthreads();

    {
        h8 a[2];
        #pragma unroll
        for (int kc = 0; kc < 2; ++kc) a[kc] = actld(XT1, 64, lane, kc);
        #pragma unroll
        for (int nt = w; nt < 8; nt += 4) {
            f32x4 acc = (f32x4){0.f,0.f,0.f,0.f};
            #pragma unroll
            for (int kc = 0; kc < 2; ++kc)
                MFMA16(acc, a[kc], frags[(size_t)(56 + nt*2 + kc)*64 + lane]);
            float bv = bi4[nt*16 + c16];
            #pragma unroll
            for (int q = 0; q < 4; ++q)
                actst(CAT, 384, rq + q, 128 + nt*16 + c16, (_Float16)relu_(acc[q] + bv));
        }
    }
    __syncthreads();

    {
        h8 a[12];
        #pragma unroll
        for (int kc = 0; kc < 12; ++kc) a[kc] = actld(CAT, 384, lane, kc);
        #pragma unroll
        for (int nt = w; nt < 8; nt += 4) {
            f32x4 acc = (f32x4){0.f,0.f,0.f,0.f};
            #pragma unroll
            for (int kc = 0; kc < 12; ++kc)
                MFMA16(acc, a[kc], frags[(size_t)(92 + nt*12 + kc)*64 + lane]);
            float bv = bcat[nt*16 + c16];
            #pragma unroll
            for (int q = 0; q < 4; ++q)
                actst(LIb, 128, rq + q, nt*16 + c16, (_Float16)relu_(acc[q] + bv));
        }
    }
    __syncthreads();

    {
        h8 a[4];
        #pragma unroll
        for (int kc = 0; kc < 4; ++kc) a[kc] = actld(LIb, 128, lane, kc);
        for (int nt = w; nt < 64; nt += 4) {
            f32x4 acc = (f32x4){0.f,0.f,0.f,0.f};
            #pragma unroll
            for (int kc = 0; kc < 4; ++kc)
                MFMA16(acc, a[kc], frags[(size_t)(188 + nt*4 + kc)*64 + lane]);
            int n = nt*16 + c16;
            int uu = n & 255, gg = n >> 8;
            float bv = bih[n] + bhh[n];
            #pragma unroll
            for (int q = 0; q < 4; ++q)
                xg4[(size_t)(r0 + rq + q)*1024 + uu*4 + gg] = acc[q] + bv;
        }
    }
}

// ---------------- pack Whh fp32 -> fp16 MFMA B-fragments (round-8) ----------
__global__ __launch_bounds__(256) void pack_whh_kernel(
    const float* __restrict__ Whh, h8* __restrict__ bregp,
    h8* __restrict__ bldsp)
{
    int i = blockIdx.x*256 + threadIdx.x;
    int w, j, kc, lane;
    bool isreg = (i < BREG_N);
    if (isreg) {
        w = i / (BREG_PW*64); int r = i % (BREG_PW*64);
        int fidx = r >> 6; lane = r & 63;
        j  = (fidx < 42) ? fidx / 6 : 7;
        kc = (fidx < 42) ? fidx % 6 : fidx - 42;
    } else {
        int L = i - BREG_N;
        if (L >= BLDS_N) return;
        w = L / (BLDS_PW*64); int r = L % (BLDS_PW*64);
        int fidx = r >> 6; lane = r & 63;
        j  = (fidx < 14) ? (fidx >> 1) : 7;
        kc = (fidx < 14) ? 6 + (fidx & 1) : 4 + (fidx - 14);
    }
    int row = 128*w + 16*j + (lane & 15);
    int col = 32*kc + 8*(lane >> 4);
    h8 v;
    #pragma unroll
    for (int e = 0; e < 8; ++e) v[e] = (_Float16)Whh[(long)row*HH + col + e];
    if (isreg) bregp[i] = v; else bldsp[i - BREG_N] = v;
}

// ------- LSTM: LB=2 batches M-packed per block, 4 blocks, 1024 gates/block --
__attribute__((amdgpu_waves_per_eu(2, 2)))
__global__ __launch_bounds__(512) void lstm_kernel(
    const float* __restrict__ xg4, const h8* __restrict__ bregp,
    const h8* __restrict__ bldsp, const float* __restrict__ h0,
    const float* __restrict__ c0, float* __restrict__ hbuf)
{
    const int u = threadIdx.x;
    const int lane = u & 63;
    const int w = u >> 6;
    const int b0 = blockIdx.x * LB;
    const int bb = u >> 8, un = u & 255;   // gate phase: thread -> (batch, unit)
    const int Bg = b0 + bb;

    __shared__ __align__(16) h8 wlds[BLDS_N];        // 144 KB
    __shared__ float gbuf[LB*1024];                  // 8 KB
    __shared__ __align__(16) char hbytes[2][LB*512]; // 2 KB (fp16, swizzled)

    for (int i = u; i < BLDS_N; i += 512) wlds[i] = bldsp[i];

    h8 bfr[BREG_PW];
    {
        const h8* bp = bregp + (size_t)(w*BREG_PW)*64 + lane;
        #pragma unroll
        for (int m = 0; m < BREG_PW; ++m) bfr[m] = bp[(size_t)m*64];
    }

    // init state: thread owns (bb, un)
    float c = c0[Bg*HH + un];
    float h_last = 0.f;
    *(_Float16*)(&hbytes[0][0] + ((bb*512 + un*2) ^ (bb<<4))) = (_Float16)h0[Bg*HH + un];
    __syncthreads();

    const char* wbase = (const char*)wlds + w*(BLDS_PW*1024);
    const int br = lane & 1;                        // A row -> batch (aliased)
    const unsigned abase = (unsigned)((br*512 + ((lane>>4)<<3)*2) ^ (br<<4));
    const float4* xp = (const float4*)xg4;

    #pragma unroll 1
    for (int t = 0; t < TT; ++t) {
        const int cb = t & 1;
        float4 xv = xp[((size_t)Bg*TT + t)*256 + un];   // (i,f,g,o) for (bb,un)

        h8 a[8];
        #pragma unroll
        for (int kc = 0; kc < 8; ++kc)
            a[kc] = *(const h8*)(&hbytes[cb][0] + (abase ^ (unsigned)(kc*64)));

        #pragma unroll
        for (int j = 0; j < 8; ++j) {
            f32x4 acc = (f32x4){0.f, 0.f, 0.f, 0.f};
            #pragma unroll
            for (int kc = 0; kc < 8; ++kc) {
                h8 bv;
                if ((j < 7) ? (kc < 6) : (kc < 4)) {
                    bv = bfr[(j < 7) ? (j*6 + kc) : (42 + kc)];
                } else {
                    unsigned off = (unsigned)(((j < 7) ? (j*2 + kc - 6)
                                                       : (14 + kc - 4))*1024 + lane*16);
                    asm volatile("" : "+v"(off));
                    bv = *(const h8*)(wbase + off);
                }
                acc = __builtin_amdgcn_mfma_f32_16x16x32_f16(a[kc], bv, acc, 0, 0, 0);
            }
            if (lane < 16) {                      // D rows 0..1 = batches
                int n = 128*w + j*16 + lane;
                gbuf[n]        = acc[0];
                gbuf[1024 + n] = acc[1];
            }
        }
        __syncthreads();

        {   // gate phase: all 512 threads, one (batch, unit) each
            float gi = gbuf[bb*1024 + un]       + xv.x;
            float gf = gbuf[bb*1024 + 256 + un] + xv.y;
            float gg = gbuf[bb*1024 + 512 + un] + xv.z;
            float go = gbuf[bb*1024 + 768 + un] + xv.w;
            c = sigmoid_(gf)*c + sigmoid_(gi)*tanhf(gg);
            float h = sigmoid_(go)*tanhf(c);
            *(_Float16*)(&hbytes[cb^1][0] + ((bb*512 + un*2) ^ (bb<<4))) = (_Float16)h;
            h_last = h;
        }
        __syncthreads();
    }
    hbuf[Bg*HH + un] = h_last;
}

// ---------------- final FC: out = relu(relu(h_T) @ Wfc + bfc) ---------------
__global__ __launch_bounds__(256) void final_fc_kernel(
    const float* __restrict__ hbuf, const float* __restrict__ Wfc,
    const float* __restrict__ bfc, float* __restrict__ out)
{
    int idx = blockIdx.x*256 + threadIdx.x;
    if (idx >= BB*N2) return;
    int b = idx / N2, j = idx - b*N2;
    const float* h = hbuf + b*HH;
    float o = bfc[j];
    for (int k = 0; k < HH; ++k) o += fmaxf(h[k], 0.f) * Wfc[(long)k*N2 + j];
    out[idx] = relu_(o);
}

extern "C" void kernel_launch(void* const* d_in, const int* in_sizes, int n_in,
                              void* d_out, int out_size, void* d_ws, size_t ws_size,
                              hipStream_t stream) {
    const float* nf     = (const float*)d_in[0];
    const int*   esrc   = (const int*)d_in[1];
    const int*   edst   = (const int*)d_in[2];
    const float* ew     = (const float*)d_in[3];
    const float* infect = (const float*)d_in[4];
    const float* temp   = (const float*)d_in[5];
    const float* h0     = (const float*)d_in[6];
    const float* c0     = (const float*)d_in[7];
    const float* Wg1    = (const float*)d_in[8];
    const float* bg1    = (const float*)d_in[9];
    const float* Wg2    = (const float*)d_in[10];
    const float* bg2    = (const float*)d_in[11];
    const float* Wgfc   = (const float*)d_in[12];
    const float* bgfc   = (const float*)d_in[13];
    const float* Wi1    = (const float*)d_in[14];
    const float* bi1    = (const float*)d_in[15];
    const float* Wi2    = (const float*)d_in[16];
    const float* bi2    = (const float*)d_in[17];
    const float* Wi3    = (const float*)d_in[18];
    const float* bi3    = (const float*)d_in[19];
    const float* Wi4    = (const float*)d_in[20];
    const float* bi4    = (const float*)d_in[21];
    const float* Wt1    = (const float*)d_in[22];
    const float* bt1    = (const float*)d_in[23];
    const float* Wt2    = (const float*)d_in[24];
    const float* bt2    = (const float*)d_in[25];
    const float* Wcat   = (const float*)d_in[26];
    const float* bcat   = (const float*)d_in[27];
    const float* Wih    = (const float*)d_in[28];
    const float* Whh    = (const float*)d_in[29];
    const float* bih    = (const float*)d_in[30];
    const float* bhh    = (const float*)d_in[31];
    const float* Wfc    = (const float*)d_in[32];
    const float* bfc    = (const float*)d_in[33];

    char* ws = (char*)d_ws;
    size_t off = 0;
    __hip_bfloat16* x2g = (__hip_bfloat16*)(ws + off); off += (size_t)BT*K2*2;
    __hip_bfloat16* WgfcT = (__hip_bfloat16*)(ws + off); off += (size_t)II*K2*2;
    float* g_pre = (float*)(ws + off); off += (size_t)BT*II*4;
    float* xg4   = (float*)(ws + off); off += (size_t)BT*1024*4;
    float* hbuf  = (float*)(ws + off); off += (size_t)BB*HH*4;
    h8* bregp = (h8*)(ws + off); off += (size_t)BREG_N*16;
    h8* bldsp = (h8*)(ws + off); off += (size_t)BLDS_N*16;
    h8* frags = (h8*)(ws + off); off += (size_t)FR_TOTAL*64*16;

    hipMemsetAsync(g_pre, 0, (size_t)BT*II*4, stream);

    pack_whh_kernel<<<128, 256, 0, stream>>>(Whh, bregp, bldsp);
    pack_frags_kernel<<<FR_TOTAL, 64, 0, stream>>>(Wi1, Wi2, Wi3, Wi4, Wt1, Wt2,
                                                   Wcat, Wih, frags);
    packT_kernel<<<(K2 + 63)/64, 256, 0, stream>>>(Wgfc, WgfcT);
    gcn_kernel<<<BT, 256, 0, stream>>>(nf, esrc, edst, ew, Wg1, bg1, Wg2, bg2, x2g);
    gemm_kernel<<<dim3(BT/GBM, GCH), 256, 0, stream>>>(x2g, WgfcT, g_pre);
    blx_kernel<<<BT/16, 256, 0, stream>>>(infect, temp, g_pre, bgfc,
                                          bi1, bi2, bi3, bi4, bt1, bt2,
                                          bcat, bih, bhh, frags, xg4);
    lstm_kernel<<<BB/LB, 512, 0, stream>>>(xg4, bregp, bldsp, h0, c0, hbuf);
    final_fc_kernel<<<(BB*N2 + 255)/256, 256, 0, stream>>>(hbuf, Wfc, bfc, (float*)d_out);
}